// Round 9
// baseline (365.305 us; speedup 1.0000x reference)
//
#include <hip/hip_runtime.h>
#include <hip/hip_bf16.h>

typedef unsigned short u16;
typedef unsigned int   u32;
typedef short bf16x8 __attribute__((ext_vector_type(8)));
typedef float f32x4  __attribute__((ext_vector_type(4)));

#define N_NODES  50000
#define N_EDGES  800000
#define DIM      64
#define N_GRAPHS 64
#define OUT_DIM  10
#define POOL_BLOCKS 256
#define POOL_CHUNK  ((N_NODES + POOL_BLOCKS - 1) / POOL_BLOCKS)   // 196

// bucket CSR build
#define BSHIFT 8
#define NBUCK  196
#define BCAP   5000
#define EPB    2048
#define NBLK_A ((N_EDGES + EPB - 1) / EPB)   // 391

__device__ __forceinline__ u16 f2bf(float f) {
    u32 u = __float_as_uint(f);
    u32 r = (u + 0x7fffu + ((u >> 16) & 1u)) >> 16;
    return (u16)r;
}
__device__ __forceinline__ float bf_lo(u32 u) { return __uint_as_float(u << 16); }
__device__ __forceinline__ float bf_hi(u32 u) { return __uint_as_float(u & 0xffff0000u); }

// ---------------- bucketed CSR build ----------------
__global__ __launch_bounds__(256) void bucket_scatter(const int* __restrict__ src,
                                                      const int* __restrict__ dst,
                                                      int* __restrict__ bcur,
                                                      u32* __restrict__ bscratch) {
    __shared__ int hist[NBUCK];
    __shared__ int base[NBUCK];
    int t = threadIdx.x;
    for (int i = t; i < NBUCK; i += 256) hist[i] = 0;
    __syncthreads();
    int e0 = blockIdx.x * EPB;
    u32 packed[8];
    int bb[8];
    #pragma unroll
    for (int i = 0; i < 8; ++i) {
        int e = e0 + i * 256 + t;
        if (e < N_EDGES) {
            int d = dst[e], s = src[e];
            bb[i] = d >> BSHIFT;
            packed[i] = ((u32)s << BSHIFT) | (u32)(d & ((1 << BSHIFT) - 1));
            atomicAdd(&hist[bb[i]], 1);
        } else bb[i] = -1;
    }
    __syncthreads();
    for (int i = t; i < NBUCK; i += 256)
        base[i] = (hist[i] > 0) ? atomicAdd(&bcur[i], hist[i]) : 0;
    __syncthreads();
    #pragma unroll
    for (int i = 0; i < 8; ++i) {
        if (bb[i] >= 0) {
            int pos = atomicAdd(&base[bb[i]], 1);
            bscratch[bb[i] * BCAP + pos] = packed[i];
        }
    }
}

// per-bucket CSR + degree histogram (LDS hist, one global add per bin)
__global__ __launch_bounds__(256) void csr_build(const u32* __restrict__ bscratch,
                                                 const int* __restrict__ bcur,
                                                 int* __restrict__ offs,
                                                 int* __restrict__ csr,
                                                 int* __restrict__ degcnt) {
    __shared__ int cnt[256];
    __shared__ int sc[256];
    __shared__ int cur2[256];
    __shared__ int gb[256];
    __shared__ int degh[256];
    int b = blockIdx.x, t = threadIdx.x;
    int vb = (t < b) ? bcur[t] : 0;
    gb[t] = vb;
    cnt[t] = 0;
    degh[t] = 0;
    __syncthreads();
    for (int d = 1; d < 256; d <<= 1) {
        int tmp = (t >= d) ? gb[t - d] : 0;
        __syncthreads();
        gb[t] += tmp;
        __syncthreads();
    }
    int gbase = gb[255];
    int n_b = bcur[b];
    const u32* bp = bscratch + (size_t)b * BCAP;
    for (int i = t; i < n_b; i += 256) atomicAdd(&cnt[bp[i] & 255], 1);
    __syncthreads();
    int v = cnt[t];
    sc[t] = v;
    int node = (b << BSHIFT) + t;
    if (node < N_NODES) atomicAdd(&degh[v > 255 ? 255 : v], 1);
    __syncthreads();
    for (int d = 1; d < 256; d <<= 1) {
        int tmp = (t >= d) ? sc[t - d] : 0;
        __syncthreads();
        sc[t] += tmp;
        __syncthreads();
    }
    int excl = sc[t] - v;
    if (node < N_NODES) offs[node] = gbase + excl;
    if (b == NBUCK - 1 && t == 0) offs[N_NODES] = N_EDGES;
    cur2[t] = gbase + excl;
    if (degh[t]) atomicAdd(&degcnt[t], degh[t]);
    __syncthreads();
    for (int i = t; i < n_b; i += 256) {
        u32 p = bp[i];
        int pos = atomicAdd(&cur2[p & 255], 1);
        csr[pos] = (int)(p >> BSHIFT);
    }
}

// counting-sort nodes by degree -> nodeord (order within bin is race-determined;
// per-node output is independent of assignment, so results stay deterministic)
__global__ __launch_bounds__(256) void deg_scatter(const int* __restrict__ offs,
                                                   const int* __restrict__ degcnt,
                                                   int* __restrict__ degcur,
                                                   int* __restrict__ nodeord) {
    __shared__ int sc[256];
    __shared__ int bs[256];
    int t = threadIdx.x;
    int v = degcnt[t];
    sc[t] = v;
    __syncthreads();
    for (int d = 1; d < 256; d <<= 1) {
        int tmp = (t >= d) ? sc[t - d] : 0;
        __syncthreads();
        sc[t] += tmp;
        __syncthreads();
    }
    bs[t] = sc[t] - v;
    __syncthreads();
    int node = blockIdx.x * 256 + t;
    if (node < N_NODES) {
        int deg = offs[node + 1] - offs[node];
        if (deg > 255) deg = 255;
        int pos = bs[deg] + atomicAdd(&degcur[deg], 1);
        nodeord[pos] = node;
    }
}

// ---------------- precompute ----------------

__global__ __launch_bounds__(256) void convert_x(const float* __restrict__ x,
                                                 u16* __restrict__ hb) {
    int c = blockIdx.x * 256 + threadIdx.x;
    if (c >= N_NODES * 8) return;
    const float* src = x + (size_t)c * 8;
    float4 f0 = *(const float4*)src;
    float4 f1 = *(const float4*)(src + 4);
    uint4 pk;
    pk.x = (u32)f2bf(f0.x) | ((u32)f2bf(f0.y) << 16);
    pk.y = (u32)f2bf(f0.z) | ((u32)f2bf(f0.w) << 16);
    pk.z = (u32)f2bf(f1.x) | ((u32)f2bf(f1.y) << 16);
    pk.w = (u32)f2bf(f1.z) | ((u32)f2bf(f1.w) << 16);
    *(uint4*)(hb + (size_t)c * 8) = pk;
}

// Mt / WvT / WsT / u precompute + zero {gsums, bcur, degcnt, degcur}
__global__ __launch_bounds__(256) void prep_mats(
    const float* __restrict__ Wq, const float* __restrict__ Wk,
    const float* __restrict__ Wv, const float* __restrict__ Ws,
    const float* __restrict__ bq,
    u16* __restrict__ Mtb, u16* __restrict__ WvTb, u16* __restrict__ WsTb,
    float* __restrict__ ubuf, float* __restrict__ gsums, int* __restrict__ bcur,
    int* __restrict__ degcnt, int* __restrict__ degcur) {
    int id = blockIdx.x * 256 + threadIdx.x;
    if (id < 2048) {
        int kc = id & 7, col = (id >> 3) & 63, l = id >> 9;
        const float* wq = Wq + l * 4096;
        const float* wk = Wk + l * 4096 + col * 64;
        u16 b[8];
        #pragma unroll
        for (int j = 0; j < 8; ++j) {
            float acc = 0.f;
            const float* wqr = wq + (kc * 8 + j) * 64;
            for (int c = 0; c < 64; ++c) acc = fmaf(wqr[c], wk[c], acc);
            b[j] = f2bf(acc);
        }
        uint4 pk;
        pk.x = (u32)b[0] | ((u32)b[1] << 16);
        pk.y = (u32)b[2] | ((u32)b[3] << 16);
        pk.z = (u32)b[4] | ((u32)b[5] << 16);
        pk.w = (u32)b[6] | ((u32)b[7] << 16);
        *(uint4*)(Mtb + ((size_t)(l * 64 + col)) * 64 + kc * 8) = pk;
    } else if (id < 6144) {
        int i2 = id & 2047;
        int kc = i2 & 7, col = (i2 >> 3) & 63, l = i2 >> 9;
        const float* W = ((id < 4096) ? Wv : Ws) + l * 4096;
        u16* out = (id < 4096) ? WvTb : WsTb;
        u16 b[8];
        #pragma unroll
        for (int j = 0; j < 8; ++j) b[j] = f2bf(W[(kc * 8 + j) * 64 + col]);
        uint4 pk;
        pk.x = (u32)b[0] | ((u32)b[1] << 16);
        pk.y = (u32)b[2] | ((u32)b[3] << 16);
        pk.z = (u32)b[4] | ((u32)b[5] << 16);
        pk.w = (u32)b[6] | ((u32)b[7] << 16);
        *(uint4*)(out + ((size_t)(l * 64 + col)) * 64 + kc * 8) = pk;
    } else if (id < 6400) {
        int i2 = id - 6144;
        int k = i2 & 63, l = i2 >> 6;
        const float* bqr = bq + l * 64;
        const float* wkr = Wk + l * 4096 + k * 64;
        float acc = 0.f;
        for (int c = 0; c < 64; ++c) acc = fmaf(bqr[c], wkr[c], acc);
        ubuf[l * 64 + k] = acc;
    } else if (id < 6400 + N_GRAPHS * DIM) {
        gsums[id - 6400] = 0.f;
    } else if (id < 6400 + N_GRAPHS * DIM + NBUCK) {
        bcur[id - 6400 - N_GRAPHS * DIM] = 0;
    } else if (id < 6400 + N_GRAPHS * DIM + NBUCK + 256) {
        degcnt[id - 6400 - N_GRAPHS * DIM - NBUCK] = 0;
    } else if (id < 6400 + N_GRAPHS * DIM + NBUCK + 512) {
        degcur[id - 6400 - N_GRAPHS * DIM - NBUCK - 256] = 0;
    }
}

// ---------------- gemm_init: qt0 = x@M0 + u0, sb0 = x@Ws0 + bs0 (both bf16) ----------------
__global__ __launch_bounds__(256) void gemm_init(
    const u16* __restrict__ hb, const u16* __restrict__ Mtb, const u16* __restrict__ WsTb,
    const float* __restrict__ ubuf, const float* __restrict__ bs,
    u16* __restrict__ qt, u16* __restrict__ sb) {
    int t = threadIdx.x;
    int wave = t >> 6, lane = t & 63;
    int nb = blockIdx.x * 64;
    int lr = lane & 15, lg4 = lane >> 4;
    int mat = wave >> 1, c0 = (wave & 1) * 2;

    const u16* bbase = (mat == 0) ? Mtb : WsTb;
    const float* bias = (mat == 0) ? ubuf : bs;

    f32x4 acc[4][2];
    #pragma unroll
    for (int c2 = 0; c2 < 2; ++c2) {
        float bval = bias[(c0 + c2) * 16 + lr];
        #pragma unroll
        for (int rt = 0; rt < 4; ++rt) acc[rt][c2] = (f32x4){bval, bval, bval, bval};
    }
    #pragma unroll
    for (int s = 0; s < 2; ++s) {
        bf16x8 af[4], bfr[2];
        #pragma unroll
        for (int rt = 0; rt < 4; ++rt) {
            int node = nb + rt * 16 + lr;
            if (node >= N_NODES) node = 0;
            af[rt] = *(const bf16x8*)(hb + (size_t)node * 64 + s * 32 + lg4 * 8);
        }
        #pragma unroll
        for (int c2 = 0; c2 < 2; ++c2)
            bfr[c2] = *(const bf16x8*)(bbase + (size_t)((c0 + c2) * 16 + lr) * 64 + s * 32 + lg4 * 8);
        #pragma unroll
        for (int rt = 0; rt < 4; ++rt)
            #pragma unroll
            for (int c2 = 0; c2 < 2; ++c2)
                acc[rt][c2] = __builtin_amdgcn_mfma_f32_16x16x32_bf16(
                    af[rt], bfr[c2], acc[rt][c2], 0, 0, 0);
    }
    u16* out = (mat == 0) ? qt : sb;
    #pragma unroll
    for (int rt = 0; rt < 4; ++rt) {
        #pragma unroll
        for (int r = 0; r < 4; ++r) {
            int node = nb + rt * 16 + lg4 * 4 + r;
            if (node >= N_NODES) continue;
            #pragma unroll
            for (int c2 = 0; c2 < 2; ++c2)
                out[(size_t)node * 64 + (c0 + c2) * 16 + lr] = f2bf(acc[rt][c2][r]);
        }
    }
}

// ---------------- edge attention: 8-lane group per node, degree-ordered ----------------
// 256 thr = 4 waves = 32 nodes/block. Lane owns 8 dims. No cross-group combine.
// h-gather software-pipelined one edge ahead.
__global__ __launch_bounds__(256) void edge_attn(
    const u16* __restrict__ qt, const u16* __restrict__ hb,
    const int* __restrict__ offs, const int* __restrict__ csr_src,
    const int* __restrict__ nodeord,
    u16* __restrict__ tb, float* __restrict__ tz) {
    int t = threadIdx.x;
    int wave = t >> 6, lane = t & 63;
    int g = lane >> 3, lg = lane & 7;
    int idx = (blockIdx.x * 4 + wave) * 8 + g;
    bool active = idx < N_NODES;
    int n = active ? nodeord[idx] : 0;
    uint4 qu = *(const uint4*)(qt + (size_t)n * 64 + lg * 8);
    float q0 = bf_lo(qu.x), q1 = bf_hi(qu.x);
    float q2 = bf_lo(qu.y), q3 = bf_hi(qu.y);
    float q4 = bf_lo(qu.z), q5 = bf_hi(qu.z);
    float q6 = bf_lo(qu.w), q7 = bf_hi(qu.w);
    int e0 = offs[n], e1 = offs[n + 1];
    if (!active) e1 = e0;
    float m = -3.0e38f, z = 0.f;
    float a8[8] = {0.f, 0.f, 0.f, 0.f, 0.f, 0.f, 0.f, 0.f};
    int e = e0;
    int s = (e < e1) ? csr_src[e] : 0;
    uint4 hu = *(const uint4*)(hb + (size_t)s * 64 + lg * 8);
    while (e < e1) {
        int en = e + 1;
        int sn = (en < e1) ? csr_src[en] : 0;
        uint4 hun = *(const uint4*)(hb + (size_t)sn * 64 + lg * 8);  // prefetch next
        float h0 = bf_lo(hu.x), h1 = bf_hi(hu.x);
        float h2 = bf_lo(hu.y), h3 = bf_hi(hu.y);
        float h4 = bf_lo(hu.z), h5 = bf_hi(hu.z);
        float h6 = bf_lo(hu.w), h7 = bf_hi(hu.w);
        float d0 = h0 * q0;
        d0 = fmaf(h1, q1, d0);
        d0 = fmaf(h2, q2, d0);
        d0 = fmaf(h3, q3, d0);
        float d1 = h4 * q4;
        d1 = fmaf(h5, q5, d1);
        d1 = fmaf(h6, q6, d1);
        d1 = fmaf(h7, q7, d1);
        float d = d0 + d1;
        d += __shfl_xor(d, 1);
        d += __shfl_xor(d, 2);
        d += __shfl_xor(d, 4);
        float alpha = d * 0.125f;              // 1/sqrt(64)
        float diff = alpha - m;
        if (__builtin_expect(diff > 25.f, 0)) {
            float c = __expf(-diff);
            z *= c;
            #pragma unroll
            for (int j = 0; j < 8; ++j) a8[j] *= c;
            m = alpha;
            diff = 0.f;
        }
        float p = __expf(diff);
        z += p;
        a8[0] = fmaf(p, h0, a8[0]);
        a8[1] = fmaf(p, h1, a8[1]);
        a8[2] = fmaf(p, h2, a8[2]);
        a8[3] = fmaf(p, h3, a8[3]);
        a8[4] = fmaf(p, h4, a8[4]);
        a8[5] = fmaf(p, h5, a8[5]);
        a8[6] = fmaf(p, h6, a8[6]);
        a8[7] = fmaf(p, h7, a8[7]);
        hu = hun;
        e = en;
    }
    if (active) {
        float invz = 1.f / (z + 1e-16f);
        uint4 pk;
        pk.x = (u32)f2bf(a8[0] * invz) | ((u32)f2bf(a8[1] * invz) << 16);
        pk.y = (u32)f2bf(a8[2] * invz) | ((u32)f2bf(a8[3] * invz) << 16);
        pk.z = (u32)f2bf(a8[4] * invz) | ((u32)f2bf(a8[5] * invz) << 16);
        pk.w = (u32)f2bf(a8[6] * invz) | ((u32)f2bf(a8[7] * invz) << 16);
        *(uint4*)(tb + (size_t)n * 64 + lg * 8) = pk;
        if (lg == 0) tz[n] = (e1 > e0) ? 1.f : 0.f;
    }
}

// ---------------- gemm_layer: h_next = t@Wv + tz*bv + sb ; then qt_next, sb_next ----------------
__global__ __launch_bounds__(256) void gemm_layer(
    const u16* __restrict__ tb, u16* __restrict__ sb, const float* __restrict__ tz,
    const u16* __restrict__ WvT, const float* __restrict__ bv,
    const u16* __restrict__ Mtn, const float* __restrict__ un,
    const u16* __restrict__ WsTn, const float* __restrict__ bsn,
    u16* __restrict__ hb, u16* __restrict__ qt) {
    __shared__ float ldsF[64 * 67];   // 17152 B
    __shared__ u16  ldsA[64 * 72];    //  9216 B
    int t = threadIdx.x;
    int wave = t >> 6, lane = t & 63;
    int nb = blockIdx.x * 64;
    int lr = lane & 15, lg4 = lane >> 4;

    f32x4 acc1[4];
    #pragma unroll
    for (int rt = 0; rt < 4; ++rt) acc1[rt] = (f32x4){0.f, 0.f, 0.f, 0.f};
    #pragma unroll
    for (int s = 0; s < 2; ++s) {
        bf16x8 af[4], bfr;
        #pragma unroll
        for (int rt = 0; rt < 4; ++rt) {
            int node = nb + rt * 16 + lr;
            if (node >= N_NODES) node = 0;
            af[rt] = *(const bf16x8*)(tb + (size_t)node * 64 + s * 32 + lg4 * 8);
        }
        bfr = *(const bf16x8*)(WvT + (size_t)(wave * 16 + lr) * 64 + s * 32 + lg4 * 8);
        #pragma unroll
        for (int rt = 0; rt < 4; ++rt)
            acc1[rt] = __builtin_amdgcn_mfma_f32_16x16x32_bf16(af[rt], bfr, acc1[rt], 0, 0, 0);
    }
    #pragma unroll
    for (int rt = 0; rt < 4; ++rt)
        #pragma unroll
        for (int r = 0; r < 4; ++r)
            ldsF[(rt * 16 + lg4 * 4 + r) * 67 + wave * 16 + lr] = acc1[rt][r];
    __syncthreads();
    {
        int row = t >> 2, cg = (t & 3) * 16;
        int node = nb + row;
        int rnode = (node < N_NODES) ? node : 0;
        const u16* sp = sb + (size_t)rnode * 64 + cg;
        uint4 s0 = *(const uint4*)sp;
        uint4 s1 = *(const uint4*)(sp + 8);
        float tzv = tz[rnode];
        float vals[16];
        float sv[16] = {
            bf_lo(s0.x), bf_hi(s0.x), bf_lo(s0.y), bf_hi(s0.y),
            bf_lo(s0.z), bf_hi(s0.z), bf_lo(s0.w), bf_hi(s0.w),
            bf_lo(s1.x), bf_hi(s1.x), bf_lo(s1.y), bf_hi(s1.y),
            bf_lo(s1.z), bf_hi(s1.z), bf_lo(s1.w), bf_hi(s1.w)};
        #pragma unroll
        for (int j = 0; j < 16; ++j)
            vals[j] = ldsF[row * 67 + cg + j] + tzv * bv[cg + j] + sv[j];
        uint4 pk0, pk1;
        u16 hb16[16];
        #pragma unroll
        for (int j = 0; j < 16; ++j) hb16[j] = f2bf(vals[j]);
        pk0.x = (u32)hb16[0] | ((u32)hb16[1] << 16);
        pk0.y = (u32)hb16[2] | ((u32)hb16[3] << 16);
        pk0.z = (u32)hb16[4] | ((u32)hb16[5] << 16);
        pk0.w = (u32)hb16[6] | ((u32)hb16[7] << 16);
        pk1.x = (u32)hb16[8] | ((u32)hb16[9] << 16);
        pk1.y = (u32)hb16[10] | ((u32)hb16[11] << 16);
        pk1.z = (u32)hb16[12] | ((u32)hb16[13] << 16);
        pk1.w = (u32)hb16[14] | ((u32)hb16[15] << 16);
        if (node < N_NODES) {
            *(uint4*)(hb + (size_t)node * 64 + cg) = pk0;
            *(uint4*)(hb + (size_t)node * 64 + cg + 8) = pk1;
        }
        *(uint4*)(ldsA + row * 72 + cg) = pk0;
        *(uint4*)(ldsA + row * 72 + cg + 8) = pk1;
    }
    __syncthreads();
    int mat = wave >> 1, c0 = (wave & 1) * 2;
    const u16* bbase = (mat == 0) ? Mtn : WsTn;
    const float* bias = (mat == 0) ? un : bsn;
    f32x4 acc2[4][2];
    #pragma unroll
    for (int c2 = 0; c2 < 2; ++c2) {
        float bval = bias[(c0 + c2) * 16 + lr];
        #pragma unroll
        for (int rt = 0; rt < 4; ++rt) acc2[rt][c2] = (f32x4){bval, bval, bval, bval};
    }
    #pragma unroll
    for (int s = 0; s < 2; ++s) {
        bf16x8 af[4], bfr[2];
        #pragma unroll
        for (int rt = 0; rt < 4; ++rt)
            af[rt] = *(const bf16x8*)(ldsA + (rt * 16 + lr) * 72 + s * 32 + lg4 * 8);
        #pragma unroll
        for (int c2 = 0; c2 < 2; ++c2)
            bfr[c2] = *(const bf16x8*)(bbase + (size_t)((c0 + c2) * 16 + lr) * 64 + s * 32 + lg4 * 8);
        #pragma unroll
        for (int rt = 0; rt < 4; ++rt)
            #pragma unroll
            for (int c2 = 0; c2 < 2; ++c2)
                acc2[rt][c2] = __builtin_amdgcn_mfma_f32_16x16x32_bf16(
                    af[rt], bfr[c2], acc2[rt][c2], 0, 0, 0);
    }
    u16* outp = (mat == 0) ? qt : sb;
    #pragma unroll
    for (int rt = 0; rt < 4; ++rt) {
        #pragma unroll
        for (int r = 0; r < 4; ++r) {
            int node = nb + rt * 16 + lg4 * 4 + r;
            if (node >= N_NODES) continue;
            #pragma unroll
            for (int c2 = 0; c2 < 2; ++c2)
                outp[(size_t)node * 64 + (c0 + c2) * 16 + lr] = f2bf(acc2[rt][c2][r]);
        }
    }
}

// ---------------- gemm_final: hfin = t@Wv + tz*bv + sb (f32) ----------------
__global__ __launch_bounds__(256) void gemm_final(
    const u16* __restrict__ tb, const u16* __restrict__ sb, const float* __restrict__ tz,
    const u16* __restrict__ WvT, const float* __restrict__ bv,
    float* __restrict__ hfin) {
    __shared__ float ldsF[64 * 67];
    int t = threadIdx.x;
    int wave = t >> 6, lane = t & 63;
    int nb = blockIdx.x * 64;
    int lr = lane & 15, lg4 = lane >> 4;

    f32x4 acc1[4];
    #pragma unroll
    for (int rt = 0; rt < 4; ++rt) acc1[rt] = (f32x4){0.f, 0.f, 0.f, 0.f};
    #pragma unroll
    for (int s = 0; s < 2; ++s) {
        bf16x8 af[4], bfr;
        #pragma unroll
        for (int rt = 0; rt < 4; ++rt) {
            int node = nb + rt * 16 + lr;
            if (node >= N_NODES) node = 0;
            af[rt] = *(const bf16x8*)(tb + (size_t)node * 64 + s * 32 + lg4 * 8);
        }
        bfr = *(const bf16x8*)(WvT + (size_t)(wave * 16 + lr) * 64 + s * 32 + lg4 * 8);
        #pragma unroll
        for (int rt = 0; rt < 4; ++rt)
            acc1[rt] = __builtin_amdgcn_mfma_f32_16x16x32_bf16(af[rt], bfr, acc1[rt], 0, 0, 0);
    }
    #pragma unroll
    for (int rt = 0; rt < 4; ++rt)
        #pragma unroll
        for (int r = 0; r < 4; ++r)
            ldsF[(rt * 16 + lg4 * 4 + r) * 67 + wave * 16 + lr] = acc1[rt][r];
    __syncthreads();
    {
        int row = t >> 2, cg = (t & 3) * 16;
        int node = nb + row;
        if (node < N_NODES) {
            const u16* sp = sb + (size_t)node * 64 + cg;
            uint4 s0 = *(const uint4*)sp;
            uint4 s1 = *(const uint4*)(sp + 8);
            float sv[16] = {
                bf_lo(s0.x), bf_hi(s0.x), bf_lo(s0.y), bf_hi(s0.y),
                bf_lo(s0.z), bf_hi(s0.z), bf_lo(s0.w), bf_hi(s0.w),
                bf_lo(s1.x), bf_hi(s1.x), bf_lo(s1.y), bf_hi(s1.y),
                bf_lo(s1.z), bf_hi(s1.z), bf_lo(s1.w), bf_hi(s1.w)};
            float tzv = tz[node];
            float* op = hfin + (size_t)node * 64 + cg;
            #pragma unroll
            for (int j4 = 0; j4 < 4; ++j4) {
                float4 o;
                o.x = ldsF[row * 67 + cg + j4 * 4 + 0] + tzv * bv[cg + j4 * 4 + 0] + sv[j4 * 4 + 0];
                o.y = ldsF[row * 67 + cg + j4 * 4 + 1] + tzv * bv[cg + j4 * 4 + 1] + sv[j4 * 4 + 1];
                o.z = ldsF[row * 67 + cg + j4 * 4 + 2] + tzv * bv[cg + j4 * 4 + 2] + sv[j4 * 4 + 2];
                o.w = ldsF[row * 67 + cg + j4 * 4 + 3] + tzv * bv[cg + j4 * 4 + 3] + sv[j4 * 4 + 3];
                *(float4*)(op + j4 * 4) = o;
            }
        }
    }
}

// ---------------- pooling ----------------
__global__ __launch_bounds__(256) void pool_sums(const float* __restrict__ h,
                                                 const int* __restrict__ batch,
                                                 float* __restrict__ gsums) {
    int b = blockIdx.x, t = threadIdx.x;
    int d = t & 63, sub = t >> 6;
    int lo = b * POOL_CHUNK;
    int hi = lo + POOL_CHUNK;
    if (hi > N_NODES) hi = N_NODES;
    float acc = 0.f;
    int curg = -1;
    for (int n = lo + sub; n < hi; n += 4) {
        int g = batch[n];
        if (g != curg) {
            if (curg >= 0) atomicAdd(&gsums[curg * 64 + d], acc);
            acc = 0.f;
            curg = g;
        }
        acc += h[(size_t)n * 64 + d];
    }
    if (curg >= 0) atomicAdd(&gsums[curg * 64 + d], acc);
}

__device__ __forceinline__ int lbound(const int* a, int n, int key) {
    int lo = 0, hi = n;
    while (lo < hi) {
        int mid = (lo + hi) >> 1;
        if (a[mid] < key) lo = mid + 1; else hi = mid;
    }
    return lo;
}

__global__ __launch_bounds__(256) void finalize(const float* __restrict__ gsums,
                                                const int* __restrict__ batch,
                                                const float* __restrict__ Wf,
                                                const float* __restrict__ bf,
                                                float* __restrict__ out) {
    __shared__ float pl[N_GRAPHS][DIM];
    __shared__ int bnd[N_GRAPHS + 1];
    int t = threadIdx.x;
    if (t <= N_GRAPHS) bnd[t] = (t == N_GRAPHS) ? N_NODES : lbound(batch, N_NODES, t);
    __syncthreads();
    for (int i = t; i < N_GRAPHS * DIM; i += 256) {
        int g = i >> 6;
        int cnt = bnd[g + 1] - bnd[g];
        pl[g][i & 63] = gsums[i] / (float)(cnt > 1 ? cnt : 1);
    }
    __syncthreads();
    for (int i = t; i < N_GRAPHS * OUT_DIM; i += 256) {
        int g = i / OUT_DIM, o = i % OUT_DIM;
        float acc = bf[o];
        #pragma unroll
        for (int d = 0; d < DIM; ++d) acc = fmaf(pl[g][d], Wf[d * OUT_DIM + o], acc);
        out[i] = acc;
    }
}

// ---------------- launch ----------------
extern "C" void kernel_launch(void* const* d_in, const int* in_sizes, int n_in,
                              void* d_out, int out_size, void* d_ws, size_t ws_size,
                              hipStream_t stream) {
    const float* x    = (const float*)d_in[0];
    const int*   ei   = (const int*)d_in[1];
    const int*   batch= (const int*)d_in[2];
    const float* Wq   = (const float*)d_in[3];
    const float* bq   = (const float*)d_in[4];
    const float* Wk   = (const float*)d_in[5];
    const float* bk   = (const float*)d_in[6];
    const float* Wv   = (const float*)d_in[7];
    const float* bv   = (const float*)d_in[8];
    const float* Ws   = (const float*)d_in[9];
    const float* bs   = (const float*)d_in[10];
    const float* Wf   = (const float*)d_in[11];
    const float* bf   = (const float*)d_in[12];
    float* out = (float*)d_out;

    char* ws = (char*)d_ws;
    u16*   qtb  = (u16*)  (ws + 0);            //  6.4 MB
    u16*   hb   = (u16*)  (ws + 6400000);      //  6.4 MB (+slack)
    u16*   tb   = (u16*)  (ws + 12808192);     //  6.4 MB (+slack)
    u16*   sbb  = (u16*)  (ws + 19216384);     //  6.4 MB
    float* hfin = (float*)(ws + 25616384);     // 12.8 MB
    u16*   Mtb  = (u16*)  (ws + 38416384);     //  32 KB
    u16*   WvTb = (u16*)  (ws + 38449152);     //  32 KB
    u16*   WsTb = (u16*)  (ws + 38481920);     //  32 KB
    float* ubuf = (float*)(ws + 38514688);     //  1 KB
    int*   bcur = (int*)  (ws + 38515712);     //  1 KB
    int*   csr  = (int*)  (ws + 38516736);     //  3.2 MB
    int*   offs = (int*)  (ws + 41716736);     //  200 KB
    u32*   bscr = (u32*)  (ws + 41917440);     //  3.92 MB
    float* gsums= (float*)(ws + 45837440);     //  16 KB
    float* tz   = (float*)(ws + 45853824);     //  200 KB
    int*   degcnt=(int*)  (ws + 46053824);     //  1 KB
    int*   degcur=(int*)  (ws + 46054848);     //  1 KB
    int*   nodeord=(int*) (ws + 46055872);     //  200 KB

    const int* srcI = ei;
    const int* dstI = ei + N_EDGES;

    prep_mats<<<44, 256, 0, stream>>>(Wq, Wk, Wv, Ws, bq, Mtb, WvTb, WsTb, ubuf,
                                      gsums, bcur, degcnt, degcur);
    convert_x<<<(N_NODES * 8 + 255) / 256, 256, 0, stream>>>(x, hb);

    bucket_scatter<<<NBLK_A, 256, 0, stream>>>(srcI, dstI, bcur, bscr);
    csr_build<<<NBUCK, 256, 0, stream>>>(bscr, bcur, offs, csr, degcnt);
    deg_scatter<<<NBUCK, 256, 0, stream>>>(offs, degcnt, degcur, nodeord);

    const int NB = (N_NODES + 63) / 64;
    const int EB = (N_NODES + 31) / 32;
    gemm_init<<<NB, 256, 0, stream>>>(hb, Mtb, WsTb, ubuf, bs, qtb, sbb);

    for (int l = 0; l < 3; ++l) {
        edge_attn<<<EB, 256, 0, stream>>>(qtb, hb, offs, csr, nodeord, tb, tz);
        gemm_layer<<<NB, 256, 0, stream>>>(
            tb, sbb, tz,
            WvTb + (size_t)l * 4096, bv + l * 64,
            Mtb + (size_t)(l + 1) * 4096, ubuf + (l + 1) * 64,
            WsTb + (size_t)(l + 1) * 4096, bs + (l + 1) * 64,
            hb, qtb);
    }
    edge_attn<<<EB, 256, 0, stream>>>(qtb, hb, offs, csr, nodeord, tb, tz);
    gemm_final<<<NB, 256, 0, stream>>>(tb, sbb, tz, WvTb + 3 * 4096, bv + 3 * 64, hfin);

    pool_sums<<<POOL_BLOCKS, 256, 0, stream>>>(hfin, batch, gsums);
    finalize<<<1, 256, 0, stream>>>(gsums, batch, Wf, bf, out);
}

// Round 10
// 260.166 us; speedup vs baseline: 1.4041x; 1.4041x over previous
//
#include <hip/hip_runtime.h>
#include <hip/hip_bf16.h>

typedef unsigned short u16;
typedef unsigned int   u32;
typedef short bf16x8 __attribute__((ext_vector_type(8)));
typedef float f32x4  __attribute__((ext_vector_type(4)));

#define N_NODES  50000
#define N_EDGES  800000
#define DIM      64
#define N_GRAPHS 64
#define OUT_DIM  10
#define POOL_BLOCKS 256
#define POOL_CHUNK  ((N_NODES + POOL_BLOCKS - 1) / POOL_BLOCKS)   // 196

// bucket CSR build
#define BSHIFT 8
#define NBUCK  196
#define BCAP   5000
#define EPB    2048
#define NBLK_A ((N_EDGES + EPB - 1) / EPB)   // 391

__device__ __forceinline__ u16 f2bf(float f) {
    u32 u = __float_as_uint(f);
    u32 r = (u + 0x7fffu + ((u >> 16) & 1u)) >> 16;
    return (u16)r;
}
__device__ __forceinline__ float bf_lo(u32 u) { return __uint_as_float(u << 16); }
__device__ __forceinline__ float bf_hi(u32 u) { return __uint_as_float(u & 0xffff0000u); }

// ---------------- bucketed CSR build ----------------
__global__ __launch_bounds__(256) void bucket_scatter(const int* __restrict__ src,
                                                      const int* __restrict__ dst,
                                                      int* __restrict__ bcur,
                                                      u32* __restrict__ bscratch) {
    __shared__ int hist[NBUCK];
    __shared__ int base[NBUCK];
    int t = threadIdx.x;
    for (int i = t; i < NBUCK; i += 256) hist[i] = 0;
    __syncthreads();
    int e0 = blockIdx.x * EPB;
    u32 packed[8];
    int bb[8];
    #pragma unroll
    for (int i = 0; i < 8; ++i) {
        int e = e0 + i * 256 + t;
        if (e < N_EDGES) {
            int d = dst[e], s = src[e];
            bb[i] = d >> BSHIFT;
            packed[i] = ((u32)s << BSHIFT) | (u32)(d & ((1 << BSHIFT) - 1));
            atomicAdd(&hist[bb[i]], 1);
        } else bb[i] = -1;
    }
    __syncthreads();
    for (int i = t; i < NBUCK; i += 256)
        base[i] = (hist[i] > 0) ? atomicAdd(&bcur[i], hist[i]) : 0;
    __syncthreads();
    #pragma unroll
    for (int i = 0; i < 8; ++i) {
        if (bb[i] >= 0) {
            int pos = atomicAdd(&base[bb[i]], 1);
            bscratch[bb[i] * BCAP + pos] = packed[i];
        }
    }
}

// per-bucket CSR + degree histogram (LDS hist, one global add per bin)
__global__ __launch_bounds__(256) void csr_build(const u32* __restrict__ bscratch,
                                                 const int* __restrict__ bcur,
                                                 int* __restrict__ offs,
                                                 int* __restrict__ csr,
                                                 int* __restrict__ degcnt) {
    __shared__ int cnt[256];
    __shared__ int sc[256];
    __shared__ int cur2[256];
    __shared__ int gb[256];
    __shared__ int degh[256];
    int b = blockIdx.x, t = threadIdx.x;
    int vb = (t < b) ? bcur[t] : 0;
    gb[t] = vb;
    cnt[t] = 0;
    degh[t] = 0;
    __syncthreads();
    for (int d = 1; d < 256; d <<= 1) {
        int tmp = (t >= d) ? gb[t - d] : 0;
        __syncthreads();
        gb[t] += tmp;
        __syncthreads();
    }
    int gbase = gb[255];
    int n_b = bcur[b];
    const u32* bp = bscratch + (size_t)b * BCAP;
    for (int i = t; i < n_b; i += 256) atomicAdd(&cnt[bp[i] & 255], 1);
    __syncthreads();
    int v = cnt[t];
    sc[t] = v;
    int node = (b << BSHIFT) + t;
    if (node < N_NODES) atomicAdd(&degh[v > 255 ? 255 : v], 1);
    __syncthreads();
    for (int d = 1; d < 256; d <<= 1) {
        int tmp = (t >= d) ? sc[t - d] : 0;
        __syncthreads();
        sc[t] += tmp;
        __syncthreads();
    }
    int excl = sc[t] - v;
    if (node < N_NODES) offs[node] = gbase + excl;
    if (b == NBUCK - 1 && t == 0) offs[N_NODES] = N_EDGES;
    cur2[t] = gbase + excl;
    if (degh[t]) atomicAdd(&degcnt[t], degh[t]);
    __syncthreads();
    for (int i = t; i < n_b; i += 256) {
        u32 p = bp[i];
        int pos = atomicAdd(&cur2[p & 255], 1);
        csr[pos] = (int)(p >> BSHIFT);
    }
}

// counting-sort nodes by degree -> nodeord.
// Two-level reservation: LDS histogram per block, ONE global atomicAdd per
// (block,bin) to reserve a run, then conflict-free scatter. (R9's version did
// one global atomicAdd per NODE on 256 bins -> ~25K-deep same-address chains
// on popular bins -> 108us. This is ~196 adds/bin total.)
__global__ __launch_bounds__(256) void deg_scatter(const int* __restrict__ offs,
                                                   const int* __restrict__ degcnt,
                                                   int* __restrict__ degcur,
                                                   int* __restrict__ nodeord) {
    __shared__ int sc[256];
    __shared__ int bs[256];
    __shared__ int hist[256];
    __shared__ int lbase[256];
    int t = threadIdx.x;
    int v = degcnt[t];
    sc[t] = v;
    hist[t] = 0;
    __syncthreads();
    for (int d = 1; d < 256; d <<= 1) {
        int tmp = (t >= d) ? sc[t - d] : 0;
        __syncthreads();
        sc[t] += tmp;
        __syncthreads();
    }
    bs[t] = sc[t] - v;   // global start of bin t
    __syncthreads();
    int node = blockIdx.x * 256 + t;
    int deg = 0, lpos = 0;
    bool act = node < N_NODES;
    if (act) {
        deg = offs[node + 1] - offs[node];
        if (deg > 255) deg = 255;
        lpos = atomicAdd(&hist[deg], 1);            // LDS atomic
    }
    __syncthreads();
    lbase[t] = (hist[t] > 0) ? atomicAdd(&degcur[t], hist[t]) : 0;  // 1 global add/bin
    __syncthreads();
    if (act) nodeord[bs[deg] + lbase[deg] + lpos] = node;
}

// ---------------- precompute ----------------

__global__ __launch_bounds__(256) void convert_x(const float* __restrict__ x,
                                                 u16* __restrict__ hb) {
    int c = blockIdx.x * 256 + threadIdx.x;
    if (c >= N_NODES * 8) return;
    const float* src = x + (size_t)c * 8;
    float4 f0 = *(const float4*)src;
    float4 f1 = *(const float4*)(src + 4);
    uint4 pk;
    pk.x = (u32)f2bf(f0.x) | ((u32)f2bf(f0.y) << 16);
    pk.y = (u32)f2bf(f0.z) | ((u32)f2bf(f0.w) << 16);
    pk.z = (u32)f2bf(f1.x) | ((u32)f2bf(f1.y) << 16);
    pk.w = (u32)f2bf(f1.z) | ((u32)f2bf(f1.w) << 16);
    *(uint4*)(hb + (size_t)c * 8) = pk;
}

// Mt / WvT / WsT / u precompute + zero {gsums, bcur, degcnt, degcur}
__global__ __launch_bounds__(256) void prep_mats(
    const float* __restrict__ Wq, const float* __restrict__ Wk,
    const float* __restrict__ Wv, const float* __restrict__ Ws,
    const float* __restrict__ bq,
    u16* __restrict__ Mtb, u16* __restrict__ WvTb, u16* __restrict__ WsTb,
    float* __restrict__ ubuf, float* __restrict__ gsums, int* __restrict__ bcur,
    int* __restrict__ degcnt, int* __restrict__ degcur) {
    int id = blockIdx.x * 256 + threadIdx.x;
    if (id < 2048) {
        int kc = id & 7, col = (id >> 3) & 63, l = id >> 9;
        const float* wq = Wq + l * 4096;
        const float* wk = Wk + l * 4096 + col * 64;
        u16 b[8];
        #pragma unroll
        for (int j = 0; j < 8; ++j) {
            float acc = 0.f;
            const float* wqr = wq + (kc * 8 + j) * 64;
            for (int c = 0; c < 64; ++c) acc = fmaf(wqr[c], wk[c], acc);
            b[j] = f2bf(acc);
        }
        uint4 pk;
        pk.x = (u32)b[0] | ((u32)b[1] << 16);
        pk.y = (u32)b[2] | ((u32)b[3] << 16);
        pk.z = (u32)b[4] | ((u32)b[5] << 16);
        pk.w = (u32)b[6] | ((u32)b[7] << 16);
        *(uint4*)(Mtb + ((size_t)(l * 64 + col)) * 64 + kc * 8) = pk;
    } else if (id < 6144) {
        int i2 = id & 2047;
        int kc = i2 & 7, col = (i2 >> 3) & 63, l = i2 >> 9;
        const float* W = ((id < 4096) ? Wv : Ws) + l * 4096;
        u16* out = (id < 4096) ? WvTb : WsTb;
        u16 b[8];
        #pragma unroll
        for (int j = 0; j < 8; ++j) b[j] = f2bf(W[(kc * 8 + j) * 64 + col]);
        uint4 pk;
        pk.x = (u32)b[0] | ((u32)b[1] << 16);
        pk.y = (u32)b[2] | ((u32)b[3] << 16);
        pk.z = (u32)b[4] | ((u32)b[5] << 16);
        pk.w = (u32)b[6] | ((u32)b[7] << 16);
        *(uint4*)(out + ((size_t)(l * 64 + col)) * 64 + kc * 8) = pk;
    } else if (id < 6400) {
        int i2 = id - 6144;
        int k = i2 & 63, l = i2 >> 6;
        const float* bqr = bq + l * 64;
        const float* wkr = Wk + l * 4096 + k * 64;
        float acc = 0.f;
        for (int c = 0; c < 64; ++c) acc = fmaf(bqr[c], wkr[c], acc);
        ubuf[l * 64 + k] = acc;
    } else if (id < 6400 + N_GRAPHS * DIM) {
        gsums[id - 6400] = 0.f;
    } else if (id < 6400 + N_GRAPHS * DIM + NBUCK) {
        bcur[id - 6400 - N_GRAPHS * DIM] = 0;
    } else if (id < 6400 + N_GRAPHS * DIM + NBUCK + 256) {
        degcnt[id - 6400 - N_GRAPHS * DIM - NBUCK] = 0;
    } else if (id < 6400 + N_GRAPHS * DIM + NBUCK + 512) {
        degcur[id - 6400 - N_GRAPHS * DIM - NBUCK - 256] = 0;
    }
}

// ---------------- gemm_init: qt0 = x@M0 + u0, sb0 = x@Ws0 + bs0 (both bf16) ----------------
__global__ __launch_bounds__(256) void gemm_init(
    const u16* __restrict__ hb, const u16* __restrict__ Mtb, const u16* __restrict__ WsTb,
    const float* __restrict__ ubuf, const float* __restrict__ bs,
    u16* __restrict__ qt, u16* __restrict__ sb) {
    int t = threadIdx.x;
    int wave = t >> 6, lane = t & 63;
    int nb = blockIdx.x * 64;
    int lr = lane & 15, lg4 = lane >> 4;
    int mat = wave >> 1, c0 = (wave & 1) * 2;

    const u16* bbase = (mat == 0) ? Mtb : WsTb;
    const float* bias = (mat == 0) ? ubuf : bs;

    f32x4 acc[4][2];
    #pragma unroll
    for (int c2 = 0; c2 < 2; ++c2) {
        float bval = bias[(c0 + c2) * 16 + lr];
        #pragma unroll
        for (int rt = 0; rt < 4; ++rt) acc[rt][c2] = (f32x4){bval, bval, bval, bval};
    }
    #pragma unroll
    for (int s = 0; s < 2; ++s) {
        bf16x8 af[4], bfr[2];
        #pragma unroll
        for (int rt = 0; rt < 4; ++rt) {
            int node = nb + rt * 16 + lr;
            if (node >= N_NODES) node = 0;
            af[rt] = *(const bf16x8*)(hb + (size_t)node * 64 + s * 32 + lg4 * 8);
        }
        #pragma unroll
        for (int c2 = 0; c2 < 2; ++c2)
            bfr[c2] = *(const bf16x8*)(bbase + (size_t)((c0 + c2) * 16 + lr) * 64 + s * 32 + lg4 * 8);
        #pragma unroll
        for (int rt = 0; rt < 4; ++rt)
            #pragma unroll
            for (int c2 = 0; c2 < 2; ++c2)
                acc[rt][c2] = __builtin_amdgcn_mfma_f32_16x16x32_bf16(
                    af[rt], bfr[c2], acc[rt][c2], 0, 0, 0);
    }
    u16* out = (mat == 0) ? qt : sb;
    #pragma unroll
    for (int rt = 0; rt < 4; ++rt) {
        #pragma unroll
        for (int r = 0; r < 4; ++r) {
            int node = nb + rt * 16 + lg4 * 4 + r;
            if (node >= N_NODES) continue;
            #pragma unroll
            for (int c2 = 0; c2 < 2; ++c2)
                out[(size_t)node * 64 + (c0 + c2) * 16 + lr] = f2bf(acc[rt][c2][r]);
        }
    }
}

// ---------------- edge attention: 8-lane group per node, degree-ordered ----------------
__global__ __launch_bounds__(256) void edge_attn(
    const u16* __restrict__ qt, const u16* __restrict__ hb,
    const int* __restrict__ offs, const int* __restrict__ csr_src,
    const int* __restrict__ nodeord,
    u16* __restrict__ tb, float* __restrict__ tz) {
    int t = threadIdx.x;
    int wave = t >> 6, lane = t & 63;
    int g = lane >> 3, lg = lane & 7;
    int idx = (blockIdx.x * 4 + wave) * 8 + g;
    bool active = idx < N_NODES;
    int n = active ? nodeord[idx] : 0;
    uint4 qu = *(const uint4*)(qt + (size_t)n * 64 + lg * 8);
    float q0 = bf_lo(qu.x), q1 = bf_hi(qu.x);
    float q2 = bf_lo(qu.y), q3 = bf_hi(qu.y);
    float q4 = bf_lo(qu.z), q5 = bf_hi(qu.z);
    float q6 = bf_lo(qu.w), q7 = bf_hi(qu.w);
    int e0 = offs[n], e1 = offs[n + 1];
    if (!active) e1 = e0;
    float m = -3.0e38f, z = 0.f;
    float a8[8] = {0.f, 0.f, 0.f, 0.f, 0.f, 0.f, 0.f, 0.f};
    int e = e0;
    int s = (e < e1) ? csr_src[e] : 0;
    uint4 hu = *(const uint4*)(hb + (size_t)s * 64 + lg * 8);
    while (e < e1) {
        int en = e + 1;
        int sn = (en < e1) ? csr_src[en] : 0;
        uint4 hun = *(const uint4*)(hb + (size_t)sn * 64 + lg * 8);  // prefetch next
        float h0 = bf_lo(hu.x), h1 = bf_hi(hu.x);
        float h2 = bf_lo(hu.y), h3 = bf_hi(hu.y);
        float h4 = bf_lo(hu.z), h5 = bf_hi(hu.z);
        float h6 = bf_lo(hu.w), h7 = bf_hi(hu.w);
        float d0 = h0 * q0;
        d0 = fmaf(h1, q1, d0);
        d0 = fmaf(h2, q2, d0);
        d0 = fmaf(h3, q3, d0);
        float d1 = h4 * q4;
        d1 = fmaf(h5, q5, d1);
        d1 = fmaf(h6, q6, d1);
        d1 = fmaf(h7, q7, d1);
        float d = d0 + d1;
        d += __shfl_xor(d, 1);
        d += __shfl_xor(d, 2);
        d += __shfl_xor(d, 4);
        float alpha = d * 0.125f;              // 1/sqrt(64)
        float diff = alpha - m;
        if (__builtin_expect(diff > 25.f, 0)) {
            float c = __expf(-diff);
            z *= c;
            #pragma unroll
            for (int j = 0; j < 8; ++j) a8[j] *= c;
            m = alpha;
            diff = 0.f;
        }
        float p = __expf(diff);
        z += p;
        a8[0] = fmaf(p, h0, a8[0]);
        a8[1] = fmaf(p, h1, a8[1]);
        a8[2] = fmaf(p, h2, a8[2]);
        a8[3] = fmaf(p, h3, a8[3]);
        a8[4] = fmaf(p, h4, a8[4]);
        a8[5] = fmaf(p, h5, a8[5]);
        a8[6] = fmaf(p, h6, a8[6]);
        a8[7] = fmaf(p, h7, a8[7]);
        hu = hun;
        e = en;
    }
    if (active) {
        float invz = 1.f / (z + 1e-16f);
        uint4 pk;
        pk.x = (u32)f2bf(a8[0] * invz) | ((u32)f2bf(a8[1] * invz) << 16);
        pk.y = (u32)f2bf(a8[2] * invz) | ((u32)f2bf(a8[3] * invz) << 16);
        pk.z = (u32)f2bf(a8[4] * invz) | ((u32)f2bf(a8[5] * invz) << 16);
        pk.w = (u32)f2bf(a8[6] * invz) | ((u32)f2bf(a8[7] * invz) << 16);
        *(uint4*)(tb + (size_t)n * 64 + lg * 8) = pk;
        if (lg == 0) tz[n] = (e1 > e0) ? 1.f : 0.f;
    }
}

// ---------------- gemm_layer: h_next = t@Wv + tz*bv + sb ; then qt_next, sb_next ----------------
__global__ __launch_bounds__(256) void gemm_layer(
    const u16* __restrict__ tb, u16* __restrict__ sb, const float* __restrict__ tz,
    const u16* __restrict__ WvT, const float* __restrict__ bv,
    const u16* __restrict__ Mtn, const float* __restrict__ un,
    const u16* __restrict__ WsTn, const float* __restrict__ bsn,
    u16* __restrict__ hb, u16* __restrict__ qt) {
    __shared__ float ldsF[64 * 67];   // 17152 B
    __shared__ u16  ldsA[64 * 72];    //  9216 B
    int t = threadIdx.x;
    int wave = t >> 6, lane = t & 63;
    int nb = blockIdx.x * 64;
    int lr = lane & 15, lg4 = lane >> 4;

    f32x4 acc1[4];
    #pragma unroll
    for (int rt = 0; rt < 4; ++rt) acc1[rt] = (f32x4){0.f, 0.f, 0.f, 0.f};
    #pragma unroll
    for (int s = 0; s < 2; ++s) {
        bf16x8 af[4], bfr;
        #pragma unroll
        for (int rt = 0; rt < 4; ++rt) {
            int node = nb + rt * 16 + lr;
            if (node >= N_NODES) node = 0;
            af[rt] = *(const bf16x8*)(tb + (size_t)node * 64 + s * 32 + lg4 * 8);
        }
        bfr = *(const bf16x8*)(WvT + (size_t)(wave * 16 + lr) * 64 + s * 32 + lg4 * 8);
        #pragma unroll
        for (int rt = 0; rt < 4; ++rt)
            acc1[rt] = __builtin_amdgcn_mfma_f32_16x16x32_bf16(af[rt], bfr, acc1[rt], 0, 0, 0);
    }
    #pragma unroll
    for (int rt = 0; rt < 4; ++rt)
        #pragma unroll
        for (int r = 0; r < 4; ++r)
            ldsF[(rt * 16 + lg4 * 4 + r) * 67 + wave * 16 + lr] = acc1[rt][r];
    __syncthreads();
    {
        int row = t >> 2, cg = (t & 3) * 16;
        int node = nb + row;
        int rnode = (node < N_NODES) ? node : 0;
        const u16* sp = sb + (size_t)rnode * 64 + cg;
        uint4 s0 = *(const uint4*)sp;
        uint4 s1 = *(const uint4*)(sp + 8);
        float tzv = tz[rnode];
        float vals[16];
        float sv[16] = {
            bf_lo(s0.x), bf_hi(s0.x), bf_lo(s0.y), bf_hi(s0.y),
            bf_lo(s0.z), bf_hi(s0.z), bf_lo(s0.w), bf_hi(s0.w),
            bf_lo(s1.x), bf_hi(s1.x), bf_lo(s1.y), bf_hi(s1.y),
            bf_lo(s1.z), bf_hi(s1.z), bf_lo(s1.w), bf_hi(s1.w)};
        #pragma unroll
        for (int j = 0; j < 16; ++j)
            vals[j] = ldsF[row * 67 + cg + j] + tzv * bv[cg + j] + sv[j];
        uint4 pk0, pk1;
        u16 hb16[16];
        #pragma unroll
        for (int j = 0; j < 16; ++j) hb16[j] = f2bf(vals[j]);
        pk0.x = (u32)hb16[0] | ((u32)hb16[1] << 16);
        pk0.y = (u32)hb16[2] | ((u32)hb16[3] << 16);
        pk0.z = (u32)hb16[4] | ((u32)hb16[5] << 16);
        pk0.w = (u32)hb16[6] | ((u32)hb16[7] << 16);
        pk1.x = (u32)hb16[8] | ((u32)hb16[9] << 16);
        pk1.y = (u32)hb16[10] | ((u32)hb16[11] << 16);
        pk1.z = (u32)hb16[12] | ((u32)hb16[13] << 16);
        pk1.w = (u32)hb16[14] | ((u32)hb16[15] << 16);
        if (node < N_NODES) {
            *(uint4*)(hb + (size_t)node * 64 + cg) = pk0;
            *(uint4*)(hb + (size_t)node * 64 + cg + 8) = pk1;
        }
        *(uint4*)(ldsA + row * 72 + cg) = pk0;
        *(uint4*)(ldsA + row * 72 + cg + 8) = pk1;
    }
    __syncthreads();
    int mat = wave >> 1, c0 = (wave & 1) * 2;
    const u16* bbase = (mat == 0) ? Mtn : WsTn;
    const float* bias = (mat == 0) ? un : bsn;
    f32x4 acc2[4][2];
    #pragma unroll
    for (int c2 = 0; c2 < 2; ++c2) {
        float bval = bias[(c0 + c2) * 16 + lr];
        #pragma unroll
        for (int rt = 0; rt < 4; ++rt) acc2[rt][c2] = (f32x4){bval, bval, bval, bval};
    }
    #pragma unroll
    for (int s = 0; s < 2; ++s) {
        bf16x8 af[4], bfr[2];
        #pragma unroll
        for (int rt = 0; rt < 4; ++rt)
            af[rt] = *(const bf16x8*)(ldsA + (rt * 16 + lr) * 72 + s * 32 + lg4 * 8);
        #pragma unroll
        for (int c2 = 0; c2 < 2; ++c2)
            bfr[c2] = *(const bf16x8*)(bbase + (size_t)((c0 + c2) * 16 + lr) * 64 + s * 32 + lg4 * 8);
        #pragma unroll
        for (int rt = 0; rt < 4; ++rt)
            #pragma unroll
            for (int c2 = 0; c2 < 2; ++c2)
                acc2[rt][c2] = __builtin_amdgcn_mfma_f32_16x16x32_bf16(
                    af[rt], bfr[c2], acc2[rt][c2], 0, 0, 0);
    }
    u16* outp = (mat == 0) ? qt : sb;
    #pragma unroll
    for (int rt = 0; rt < 4; ++rt) {
        #pragma unroll
        for (int r = 0; r < 4; ++r) {
            int node = nb + rt * 16 + lg4 * 4 + r;
            if (node >= N_NODES) continue;
            #pragma unroll
            for (int c2 = 0; c2 < 2; ++c2)
                outp[(size_t)node * 64 + (c0 + c2) * 16 + lr] = f2bf(acc2[rt][c2][r]);
        }
    }
}

// ---------------- gemm_final: hfin = t@Wv + tz*bv + sb (f32) ----------------
__global__ __launch_bounds__(256) void gemm_final(
    const u16* __restrict__ tb, const u16* __restrict__ sb, const float* __restrict__ tz,
    const u16* __restrict__ WvT, const float* __restrict__ bv,
    float* __restrict__ hfin) {
    __shared__ float ldsF[64 * 67];
    int t = threadIdx.x;
    int wave = t >> 6, lane = t & 63;
    int nb = blockIdx.x * 64;
    int lr = lane & 15, lg4 = lane >> 4;

    f32x4 acc1[4];
    #pragma unroll
    for (int rt = 0; rt < 4; ++rt) acc1[rt] = (f32x4){0.f, 0.f, 0.f, 0.f};
    #pragma unroll
    for (int s = 0; s < 2; ++s) {
        bf16x8 af[4], bfr;
        #pragma unroll
        for (int rt = 0; rt < 4; ++rt) {
            int node = nb + rt * 16 + lr;
            if (node >= N_NODES) node = 0;
            af[rt] = *(const bf16x8*)(tb + (size_t)node * 64 + s * 32 + lg4 * 8);
        }
        bfr = *(const bf16x8*)(WvT + (size_t)(wave * 16 + lr) * 64 + s * 32 + lg4 * 8);
        #pragma unroll
        for (int rt = 0; rt < 4; ++rt)
            acc1[rt] = __builtin_amdgcn_mfma_f32_16x16x32_bf16(af[rt], bfr, acc1[rt], 0, 0, 0);
    }
    #pragma unroll
    for (int rt = 0; rt < 4; ++rt)
        #pragma unroll
        for (int r = 0; r < 4; ++r)
            ldsF[(rt * 16 + lg4 * 4 + r) * 67 + wave * 16 + lr] = acc1[rt][r];
    __syncthreads();
    {
        int row = t >> 2, cg = (t & 3) * 16;
        int node = nb + row;
        if (node < N_NODES) {
            const u16* sp = sb + (size_t)node * 64 + cg;
            uint4 s0 = *(const uint4*)sp;
            uint4 s1 = *(const uint4*)(sp + 8);
            float sv[16] = {
                bf_lo(s0.x), bf_hi(s0.x), bf_lo(s0.y), bf_hi(s0.y),
                bf_lo(s0.z), bf_hi(s0.z), bf_lo(s0.w), bf_hi(s0.w),
                bf_lo(s1.x), bf_hi(s1.x), bf_lo(s1.y), bf_hi(s1.y),
                bf_lo(s1.z), bf_hi(s1.z), bf_lo(s1.w), bf_hi(s1.w)};
            float tzv = tz[node];
            float* op = hfin + (size_t)node * 64 + cg;
            #pragma unroll
            for (int j4 = 0; j4 < 4; ++j4) {
                float4 o;
                o.x = ldsF[row * 67 + cg + j4 * 4 + 0] + tzv * bv[cg + j4 * 4 + 0] + sv[j4 * 4 + 0];
                o.y = ldsF[row * 67 + cg + j4 * 4 + 1] + tzv * bv[cg + j4 * 4 + 1] + sv[j4 * 4 + 1];
                o.z = ldsF[row * 67 + cg + j4 * 4 + 2] + tzv * bv[cg + j4 * 4 + 2] + sv[j4 * 4 + 2];
                o.w = ldsF[row * 67 + cg + j4 * 4 + 3] + tzv * bv[cg + j4 * 4 + 3] + sv[j4 * 4 + 3];
                *(float4*)(op + j4 * 4) = o;
            }
        }
    }
}

// ---------------- pooling ----------------
__global__ __launch_bounds__(256) void pool_sums(const float* __restrict__ h,
                                                 const int* __restrict__ batch,
                                                 float* __restrict__ gsums) {
    int b = blockIdx.x, t = threadIdx.x;
    int d = t & 63, sub = t >> 6;
    int lo = b * POOL_CHUNK;
    int hi = lo + POOL_CHUNK;
    if (hi > N_NODES) hi = N_NODES;
    float acc = 0.f;
    int curg = -1;
    for (int n = lo + sub; n < hi; n += 4) {
        int g = batch[n];
        if (g != curg) {
            if (curg >= 0) atomicAdd(&gsums[curg * 64 + d], acc);
            acc = 0.f;
            curg = g;
        }
        acc += h[(size_t)n * 64 + d];
    }
    if (curg >= 0) atomicAdd(&gsums[curg * 64 + d], acc);
}

__device__ __forceinline__ int lbound(const int* a, int n, int key) {
    int lo = 0, hi = n;
    while (lo < hi) {
        int mid = (lo + hi) >> 1;
        if (a[mid] < key) lo = mid + 1; else hi = mid;
    }
    return lo;
}

__global__ __launch_bounds__(256) void finalize(const float* __restrict__ gsums,
                                                const int* __restrict__ batch,
                                                const float* __restrict__ Wf,
                                                const float* __restrict__ bf,
                                                float* __restrict__ out) {
    __shared__ float pl[N_GRAPHS][DIM];
    __shared__ int bnd[N_GRAPHS + 1];
    int t = threadIdx.x;
    if (t <= N_GRAPHS) bnd[t] = (t == N_GRAPHS) ? N_NODES : lbound(batch, N_NODES, t);
    __syncthreads();
    for (int i = t; i < N_GRAPHS * DIM; i += 256) {
        int g = i >> 6;
        int cnt = bnd[g + 1] - bnd[g];
        pl[g][i & 63] = gsums[i] / (float)(cnt > 1 ? cnt : 1);
    }
    __syncthreads();
    for (int i = t; i < N_GRAPHS * OUT_DIM; i += 256) {
        int g = i / OUT_DIM, o = i % OUT_DIM;
        float acc = bf[o];
        #pragma unroll
        for (int d = 0; d < DIM; ++d) acc = fmaf(pl[g][d], Wf[d * OUT_DIM + o], acc);
        out[i] = acc;
    }
}

// ---------------- launch ----------------
extern "C" void kernel_launch(void* const* d_in, const int* in_sizes, int n_in,
                              void* d_out, int out_size, void* d_ws, size_t ws_size,
                              hipStream_t stream) {
    const float* x    = (const float*)d_in[0];
    const int*   ei   = (const int*)d_in[1];
    const int*   batch= (const int*)d_in[2];
    const float* Wq   = (const float*)d_in[3];
    const float* bq   = (const float*)d_in[4];
    const float* Wk   = (const float*)d_in[5];
    const float* bk   = (const float*)d_in[6];
    const float* Wv   = (const float*)d_in[7];
    const float* bv   = (const float*)d_in[8];
    const float* Ws   = (const float*)d_in[9];
    const float* bs   = (const float*)d_in[10];
    const float* Wf   = (const float*)d_in[11];
    const float* bf   = (const float*)d_in[12];
    float* out = (float*)d_out;

    char* ws = (char*)d_ws;
    u16*   qtb  = (u16*)  (ws + 0);            //  6.4 MB
    u16*   hb   = (u16*)  (ws + 6400000);      //  6.4 MB (+slack)
    u16*   tb   = (u16*)  (ws + 12808192);     //  6.4 MB (+slack)
    u16*   sbb  = (u16*)  (ws + 19216384);     //  6.4 MB
    float* hfin = (float*)(ws + 25616384);     // 12.8 MB
    u16*   Mtb  = (u16*)  (ws + 38416384);     //  32 KB
    u16*   WvTb = (u16*)  (ws + 38449152);     //  32 KB
    u16*   WsTb = (u16*)  (ws + 38481920);     //  32 KB
    float* ubuf = (float*)(ws + 38514688);     //  1 KB
    int*   bcur = (int*)  (ws + 38515712);     //  1 KB
    int*   csr  = (int*)  (ws + 38516736);     //  3.2 MB
    int*   offs = (int*)  (ws + 41716736);     //  200 KB
    u32*   bscr = (u32*)  (ws + 41917440);     //  3.92 MB
    float* gsums= (float*)(ws + 45837440);     //  16 KB
    float* tz   = (float*)(ws + 45853824);     //  200 KB
    int*   degcnt=(int*)  (ws + 46053824);     //  1 KB
    int*   degcur=(int*)  (ws + 46054848);     //  1 KB
    int*   nodeord=(int*) (ws + 46055872);     //  200 KB

    const int* srcI = ei;
    const int* dstI = ei + N_EDGES;

    prep_mats<<<44, 256, 0, stream>>>(Wq, Wk, Wv, Ws, bq, Mtb, WvTb, WsTb, ubuf,
                                      gsums, bcur, degcnt, degcur);
    convert_x<<<(N_NODES * 8 + 255) / 256, 256, 0, stream>>>(x, hb);

    bucket_scatter<<<NBLK_A, 256, 0, stream>>>(srcI, dstI, bcur, bscr);
    csr_build<<<NBUCK, 256, 0, stream>>>(bscr, bcur, offs, csr, degcnt);
    deg_scatter<<<NBUCK, 256, 0, stream>>>(offs, degcnt, degcur, nodeord);

    const int NB = (N_NODES + 63) / 64;
    const int EB = (N_NODES + 31) / 32;
    gemm_init<<<NB, 256, 0, stream>>>(hb, Mtb, WsTb, ubuf, bs, qtb, sbb);

    for (int l = 0; l < 3; ++l) {
        edge_attn<<<EB, 256, 0, stream>>>(qtb, hb, offs, csr, nodeord, tb, tz);
        gemm_layer<<<NB, 256, 0, stream>>>(
            tb, sbb, tz,
            WvTb + (size_t)l * 4096, bv + l * 64,
            Mtb + (size_t)(l + 1) * 4096, ubuf + (l + 1) * 64,
            WsTb + (size_t)(l + 1) * 4096, bs + (l + 1) * 64,
            hb, qtb);
    }
    edge_attn<<<EB, 256, 0, stream>>>(qtb, hb, offs, csr, nodeord, tb, tz);
    gemm_final<<<NB, 256, 0, stream>>>(tb, sbb, tz, WvTb + 3 * 4096, bv + 3 * 64, hfin);

    pool_sums<<<POOL_BLOCKS, 256, 0, stream>>>(hfin, batch, gsums);
    finalize<<<1, 256, 0, stream>>>(gsums, batch, Wf, bf, out);
}

// Round 12
// 256.292 us; speedup vs baseline: 1.4253x; 1.0151x over previous
//
#include <hip/hip_runtime.h>
#include <hip/hip_fp16.h>

typedef unsigned short u16;
typedef unsigned int   u32;
typedef _Float16 f16x8 __attribute__((ext_vector_type(8)));
typedef float    f32x4 __attribute__((ext_vector_type(4)));

#define N_NODES  50000
#define N_EDGES  800000
#define DIM      64
#define N_GRAPHS 64
#define OUT_DIM  10
#define POOL_BLOCKS 256
#define POOL_CHUNK  ((N_NODES + POOL_BLOCKS - 1) / POOL_BLOCKS)   // 196

#define BSHIFT 8
#define NBUCK  196
#define BCAP   5000
#define EPB    2048
#define NBLK_A ((N_EDGES + EPB - 1) / EPB)   // 391

__device__ __forceinline__ u16 h16(float f) {
    return __half_as_ushort(__float2half_rn(f));
}
__device__ __forceinline__ __half2 bch(u32 v) {
    union { u32 u; __half2 h; } x; x.u = v; return x.h;
}
__device__ __forceinline__ u32 pkh(float a, float b) {
    union { u32 u; __half2 h; } x; x.h = __floats2half2_rn(a, b); return x.u;
}

// ---------------- bucketed CSR build ----------------
__global__ __launch_bounds__(256) void bucket_scatter(const int* __restrict__ src,
                                                      const int* __restrict__ dst,
                                                      int* __restrict__ bcur,
                                                      u32* __restrict__ bscratch) {
    __shared__ int hist[NBUCK];
    __shared__ int base[NBUCK];
    int t = threadIdx.x;
    for (int i = t; i < NBUCK; i += 256) hist[i] = 0;
    __syncthreads();
    int e0 = blockIdx.x * EPB;
    u32 packed[8];
    int bb[8];
    #pragma unroll
    for (int i = 0; i < 8; ++i) {
        int e = e0 + i * 256 + t;
        if (e < N_EDGES) {
            int d = dst[e], s = src[e];
            bb[i] = d >> BSHIFT;
            packed[i] = ((u32)s << BSHIFT) | (u32)(d & ((1 << BSHIFT) - 1));
            atomicAdd(&hist[bb[i]], 1);
        } else bb[i] = -1;
    }
    __syncthreads();
    for (int i = t; i < NBUCK; i += 256)
        base[i] = (hist[i] > 0) ? atomicAdd(&bcur[i], hist[i]) : 0;
    __syncthreads();
    #pragma unroll
    for (int i = 0; i < 8; ++i) {
        if (bb[i] >= 0) {
            int pos = atomicAdd(&base[bb[i]], 1);
            bscratch[bb[i] * BCAP + pos] = packed[i];
        }
    }
}

__global__ __launch_bounds__(256) void csr_build(const u32* __restrict__ bscratch,
                                                 const int* __restrict__ bcur,
                                                 int* __restrict__ offs,
                                                 int* __restrict__ csr) {
    __shared__ int cnt[256];
    __shared__ int sc[256];
    __shared__ int cur2[256];
    __shared__ int gb[256];
    int b = blockIdx.x, t = threadIdx.x;
    int vb = (t < b) ? bcur[t] : 0;
    gb[t] = vb;
    cnt[t] = 0;
    __syncthreads();
    for (int d = 1; d < 256; d <<= 1) {
        int tmp = (t >= d) ? gb[t - d] : 0;
        __syncthreads();
        gb[t] += tmp;
        __syncthreads();
    }
    int gbase = gb[255];
    int n_b = bcur[b];
    const u32* bp = bscratch + (size_t)b * BCAP;
    for (int i = t; i < n_b; i += 256) atomicAdd(&cnt[bp[i] & 255], 1);
    __syncthreads();
    int v = cnt[t];
    sc[t] = v;
    __syncthreads();
    for (int d = 1; d < 256; d <<= 1) {
        int tmp = (t >= d) ? sc[t - d] : 0;
        __syncthreads();
        sc[t] += tmp;
        __syncthreads();
    }
    int excl = sc[t] - v;
    int node = (b << BSHIFT) + t;
    if (node < N_NODES) offs[node] = gbase + excl;
    if (b == NBUCK - 1 && t == 0) offs[N_NODES] = N_EDGES;
    cur2[t] = gbase + excl;
    __syncthreads();
    for (int i = t; i < n_b; i += 256) {
        u32 p = bp[i];
        int pos = atomicAdd(&cur2[p & 255], 1);
        csr[pos] = (int)(p >> BSHIFT);
    }
}

// ---------------- precompute ----------------

__global__ __launch_bounds__(256) void convert_x(const float* __restrict__ x,
                                                 u16* __restrict__ hb) {
    int c = blockIdx.x * 256 + threadIdx.x;
    if (c >= N_NODES * 8) return;
    const float* src = x + (size_t)c * 8;
    float4 f0 = *(const float4*)src;
    float4 f1 = *(const float4*)(src + 4);
    uint4 pk;
    pk.x = pkh(f0.x, f0.y);
    pk.y = pkh(f0.z, f0.w);
    pk.z = pkh(f1.x, f1.y);
    pk.w = pkh(f1.z, f1.w);
    *(uint4*)(hb + (size_t)c * 8) = pk;
}

// Mt[l][col][k]=sum_c Wq[l][k][c]*Wk[l][col][c]; WvT/WsT transposes; u; zero gsums/bcur
__global__ __launch_bounds__(256) void prep_mats(
    const float* __restrict__ Wq, const float* __restrict__ Wk,
    const float* __restrict__ Wv, const float* __restrict__ Ws,
    const float* __restrict__ bq,
    u16* __restrict__ Mtb, u16* __restrict__ WvTb, u16* __restrict__ WsTb,
    float* __restrict__ ubuf, float* __restrict__ gsums, int* __restrict__ bcur) {
    int id = blockIdx.x * 256 + threadIdx.x;
    if (id < 2048) {
        int kc = id & 7, col = (id >> 3) & 63, l = id >> 9;
        const float* wq = Wq + l * 4096;
        const float* wk = Wk + l * 4096 + col * 64;
        u16 b[8];
        #pragma unroll
        for (int j = 0; j < 8; ++j) {
            float acc = 0.f;
            const float* wqr = wq + (kc * 8 + j) * 64;
            for (int c = 0; c < 64; ++c) acc = fmaf(wqr[c], wk[c], acc);
            b[j] = h16(acc);
        }
        uint4 pk;
        pk.x = (u32)b[0] | ((u32)b[1] << 16);
        pk.y = (u32)b[2] | ((u32)b[3] << 16);
        pk.z = (u32)b[4] | ((u32)b[5] << 16);
        pk.w = (u32)b[6] | ((u32)b[7] << 16);
        *(uint4*)(Mtb + ((size_t)(l * 64 + col)) * 64 + kc * 8) = pk;
    } else if (id < 6144) {
        int i2 = id & 2047;
        int kc = i2 & 7, col = (i2 >> 3) & 63, l = i2 >> 9;
        const float* W = ((id < 4096) ? Wv : Ws) + l * 4096;
        u16* out = (id < 4096) ? WvTb : WsTb;
        u16 b[8];
        #pragma unroll
        for (int j = 0; j < 8; ++j) b[j] = h16(W[(kc * 8 + j) * 64 + col]);
        uint4 pk;
        pk.x = (u32)b[0] | ((u32)b[1] << 16);
        pk.y = (u32)b[2] | ((u32)b[3] << 16);
        pk.z = (u32)b[4] | ((u32)b[5] << 16);
        pk.w = (u32)b[6] | ((u32)b[7] << 16);
        *(uint4*)(out + ((size_t)(l * 64 + col)) * 64 + kc * 8) = pk;
    } else if (id < 6400) {
        int i2 = id - 6144;
        int k = i2 & 63, l = i2 >> 6;
        const float* bqr = bq + l * 64;
        const float* wkr = Wk + l * 4096 + k * 64;
        float acc = 0.f;
        for (int c = 0; c < 64; ++c) acc = fmaf(bqr[c], wkr[c], acc);
        ubuf[l * 64 + k] = acc;
    } else if (id < 6400 + N_GRAPHS * DIM) {
        gsums[id - 6400] = 0.f;
    } else if (id < 6400 + N_GRAPHS * DIM + NBUCK) {
        bcur[id - 6400 - N_GRAPHS * DIM] = 0;
    }
}

// ---------------- gemm_init: qt0 = x@M0 + u0, sb0 = x@Ws0 + bs0 (f16) ----------------
__global__ __launch_bounds__(256) void gemm_init(
    const u16* __restrict__ hb, const u16* __restrict__ Mtb, const u16* __restrict__ WsTb,
    const float* __restrict__ ubuf, const float* __restrict__ bs,
    u16* __restrict__ qt, u16* __restrict__ sb) {
    int t = threadIdx.x;
    int wave = t >> 6, lane = t & 63;
    int nb = blockIdx.x * 64;
    int lr = lane & 15, lg4 = lane >> 4;
    int mat = wave >> 1, c0 = (wave & 1) * 2;

    const u16* bbase = (mat == 0) ? Mtb : WsTb;
    const float* bias = (mat == 0) ? ubuf : bs;

    f32x4 acc[4][2];
    #pragma unroll
    for (int c2 = 0; c2 < 2; ++c2) {
        float bval = bias[(c0 + c2) * 16 + lr];
        #pragma unroll
        for (int rt = 0; rt < 4; ++rt) acc[rt][c2] = (f32x4){bval, bval, bval, bval};
    }
    #pragma unroll
    for (int s = 0; s < 2; ++s) {
        f16x8 af[4], bfr[2];
        #pragma unroll
        for (int rt = 0; rt < 4; ++rt) {
            int node = nb + rt * 16 + lr;
            if (node >= N_NODES) node = 0;
            af[rt] = *(const f16x8*)(hb + (size_t)node * 64 + s * 32 + lg4 * 8);
        }
        #pragma unroll
        for (int c2 = 0; c2 < 2; ++c2)
            bfr[c2] = *(const f16x8*)(bbase + (size_t)((c0 + c2) * 16 + lr) * 64 + s * 32 + lg4 * 8);
        #pragma unroll
        for (int rt = 0; rt < 4; ++rt)
            #pragma unroll
            for (int c2 = 0; c2 < 2; ++c2)
                acc[rt][c2] = __builtin_amdgcn_mfma_f32_16x16x32_f16(
                    af[rt], bfr[c2], acc[rt][c2], 0, 0, 0);
    }
    u16* out = (mat == 0) ? qt : sb;
    #pragma unroll
    for (int rt = 0; rt < 4; ++rt) {
        #pragma unroll
        for (int r = 0; r < 4; ++r) {
            int node = nb + rt * 16 + lg4 * 4 + r;
            if (node >= N_NODES) continue;
            #pragma unroll
            for (int c2 = 0; c2 < 2; ++c2)
                out[(size_t)node * 64 + (c0 + c2) * 16 + lr] = h16(acc[rt][c2][r]);
        }
    }
}

// ---------------- fused layer: edge attention (LDS t) + 3 GEMMs ----------------
// block = 256 thr, owns nodes [nb, nb+64). Phase E: STATIC assignment — group
// g (32 groups of 8 lanes) handles local nodes g and g+32 (no atomics, no
// cross-lane broadcast; divergence pattern identical to R10's proven kernel).
// Phase G: t@Wv (MFMA from LDS) -> +tz*bv+sb -> h_next (hbout f16 / hfin16 if
// last) -> qt_next = h@M+u, sb_next = h@Ws+bs (MFMA from LDS).
__global__ __launch_bounds__(256) void layer_fused(
    const int* __restrict__ offs, const int* __restrict__ csr,
    u16* __restrict__ qt, u16* __restrict__ sb,
    const u16* __restrict__ hbin, u16* __restrict__ hbout,
    const u16* __restrict__ WvT, const float* __restrict__ bv,
    const u16* __restrict__ Mtn, const float* __restrict__ un,
    const u16* __restrict__ WsTn, const float* __restrict__ bsn,
    u16* __restrict__ hfin16, int last) {
    __shared__ u16  ldsT[64 * 72];    //  9216 B : t (E->1), then h_next (3->4)
    __shared__ float ldsF[64 * 67];   // 17152 B
    __shared__ float ldsZ[64];
    int t = threadIdx.x;
    int wave = t >> 6, lane = t & 63;
    int nb = blockIdx.x * 64;
    int lr = lane & 15, lg4 = lane >> 4;
    int lg = lane & 7;
    int grp = wave * 8 + (lane >> 3);   // 0..31

    // ---- Phase E: two fixed rounds ----
    #pragma unroll
    for (int it = 0; it < 2; ++it) {
        int myn = grp + it * 32;          // 0..63
        int node = nb + myn;
        bool valid = node < N_NODES;
        int rn = valid ? node : 0;
        uint4 qraw = *(const uint4*)(qt + (size_t)rn * 64 + lg * 8);
        __half2 q01 = bch(qraw.x), q23 = bch(qraw.y), q45 = bch(qraw.z), q67 = bch(qraw.w);
        int e0 = valid ? offs[node] : 0;
        int e1 = valid ? offs[node + 1] : 0;
        float m = -3.0e38f, z = 0.f;
        __half2 zero2 = __float2half2_rn(0.f);
        __half2 a01 = zero2, a23 = zero2, a45 = zero2, a67 = zero2;
        int e = e0;
        int s = (e < e1) ? csr[e] : 0;
        uint4 hu = *(const uint4*)(hbin + (size_t)s * 64 + lg * 8);
        while (e < e1) {
            int en = e + 1;
            int sn = (en < e1) ? csr[en] : 0;
            uint4 hun = *(const uint4*)(hbin + (size_t)sn * 64 + lg * 8);  // prefetch
            __half2 h01 = bch(hu.x), h23 = bch(hu.y), h45 = bch(hu.z), h67 = bch(hu.w);
            __half2 d2 = __hmul2(h01, q01);
            d2 = __hfma2(h23, q23, d2);
            d2 = __hfma2(h45, q45, d2);
            d2 = __hfma2(h67, q67, d2);
            float d = __low2float(d2) + __high2float(d2);
            d += __shfl_xor(d, 1);
            d += __shfl_xor(d, 2);
            d += __shfl_xor(d, 4);
            float alpha = d * 0.125f;               // 1/sqrt(64)
            float diff = alpha - m;
            if (__builtin_expect(diff > 4.f, 0)) {  // keep p <= e^4 for f16 accum
                float c = __expf(-diff);
                z *= c;
                __half2 ch = __float2half2_rn(c);
                a01 = __hmul2(a01, ch); a23 = __hmul2(a23, ch);
                a45 = __hmul2(a45, ch); a67 = __hmul2(a67, ch);
                m = alpha; diff = 0.f;
            }
            float p = __expf(diff);
            z += p;
            __half2 ph = __float2half2_rn(p);
            a01 = __hfma2(ph, h01, a01);
            a23 = __hfma2(ph, h23, a23);
            a45 = __hfma2(ph, h45, a45);
            a67 = __hfma2(ph, h67, a67);
            hu = hun; e = en;
        }
        // always store (invalid rows produce zeros) so ldsT/ldsZ fully init'd
        float invz = 1.f / (z + 1e-16f);
        uint4 pk;
        pk.x = pkh(__low2float(a01) * invz, __high2float(a01) * invz);
        pk.y = pkh(__low2float(a23) * invz, __high2float(a23) * invz);
        pk.z = pkh(__low2float(a45) * invz, __high2float(a45) * invz);
        pk.w = pkh(__low2float(a67) * invz, __high2float(a67) * invz);
        *(uint4*)(ldsT + myn * 72 + lg * 8) = pk;
        if (lg == 0) ldsZ[myn] = (e1 > e0) ? 1.f : 0.f;
    }
    __syncthreads();

    // ---- Phase 1: t @ WvT (wave w -> cols w*16..w*16+15), A from ldsT ----
    f32x4 acc1[4];
    #pragma unroll
    for (int rt = 0; rt < 4; ++rt) acc1[rt] = (f32x4){0.f, 0.f, 0.f, 0.f};
    #pragma unroll
    for (int s = 0; s < 2; ++s) {
        f16x8 af[4], bfr;
        #pragma unroll
        for (int rt = 0; rt < 4; ++rt)
            af[rt] = *(const f16x8*)(ldsT + (rt * 16 + lr) * 72 + s * 32 + lg4 * 8);
        bfr = *(const f16x8*)(WvT + (size_t)(wave * 16 + lr) * 64 + s * 32 + lg4 * 8);
        #pragma unroll
        for (int rt = 0; rt < 4; ++rt)
            acc1[rt] = __builtin_amdgcn_mfma_f32_16x16x32_f16(af[rt], bfr, acc1[rt], 0, 0, 0);
    }
    // ---- Phase 2: stash f32 to ldsF ----
    #pragma unroll
    for (int rt = 0; rt < 4; ++rt)
        #pragma unroll
        for (int r = 0; r < 4; ++r)
            ldsF[(rt * 16 + lg4 * 4 + r) * 67 + wave * 16 + lr] = acc1[rt][r];
    __syncthreads();
    // ---- Phase 3: h_next = ldsF + tz*bv + sb -> (hbout|hfin16) + ldsT ----
    {
        int row = t >> 2, cg = (t & 3) * 16;
        int node = nb + row;
        int rnode = (node < N_NODES) ? node : 0;
        const u16* sp = sb + (size_t)rnode * 64 + cg;
        uint4 s0 = *(const uint4*)sp;
        uint4 s1 = *(const uint4*)(sp + 8);
        float sv[16];
        {
            __half2 x0 = bch(s0.x), x1 = bch(s0.y), x2 = bch(s0.z), x3 = bch(s0.w);
            __half2 x4 = bch(s1.x), x5 = bch(s1.y), x6 = bch(s1.z), x7 = bch(s1.w);
            sv[0] = __low2float(x0);  sv[1] = __high2float(x0);
            sv[2] = __low2float(x1);  sv[3] = __high2float(x1);
            sv[4] = __low2float(x2);  sv[5] = __high2float(x2);
            sv[6] = __low2float(x3);  sv[7] = __high2float(x3);
            sv[8] = __low2float(x4);  sv[9] = __high2float(x4);
            sv[10] = __low2float(x5); sv[11] = __high2float(x5);
            sv[12] = __low2float(x6); sv[13] = __high2float(x6);
            sv[14] = __low2float(x7); sv[15] = __high2float(x7);
        }
        float tzv = ldsZ[row];
        float vals[16];
        #pragma unroll
        for (int j = 0; j < 16; ++j)
            vals[j] = ldsF[row * 67 + cg + j] + tzv * bv[cg + j] + sv[j];
        uint4 pk0, pk1;
        pk0.x = pkh(vals[0], vals[1]);
        pk0.y = pkh(vals[2], vals[3]);
        pk0.z = pkh(vals[4], vals[5]);
        pk0.w = pkh(vals[6], vals[7]);
        pk1.x = pkh(vals[8], vals[9]);
        pk1.y = pkh(vals[10], vals[11]);
        pk1.z = pkh(vals[12], vals[13]);
        pk1.w = pkh(vals[14], vals[15]);
        if (node < N_NODES) {
            u16* dst = last ? hfin16 : hbout;
            *(uint4*)(dst + (size_t)node * 64 + cg) = pk0;
            *(uint4*)(dst + (size_t)node * 64 + cg + 8) = pk1;
        }
        *(uint4*)(ldsT + row * 72 + cg) = pk0;
        *(uint4*)(ldsT + row * 72 + cg + 8) = pk1;
    }
    if (last) return;
    __syncthreads();
    // ---- Phase 4: qt_next (waves 0,1) / sb_next (waves 2,3) from ldsT ----
    int mat = wave >> 1, c0 = (wave & 1) * 2;
    const u16* bbase = (mat == 0) ? Mtn : WsTn;
    const float* bias = (mat == 0) ? un : bsn;
    f32x4 acc2[4][2];
    #pragma unroll
    for (int c2 = 0; c2 < 2; ++c2) {
        float bval = bias[(c0 + c2) * 16 + lr];
        #pragma unroll
        for (int rt = 0; rt < 4; ++rt) acc2[rt][c2] = (f32x4){bval, bval, bval, bval};
    }
    #pragma unroll
    for (int s = 0; s < 2; ++s) {
        f16x8 af[4], bfr[2];
        #pragma unroll
        for (int rt = 0; rt < 4; ++rt)
            af[rt] = *(const f16x8*)(ldsT + (rt * 16 + lr) * 72 + s * 32 + lg4 * 8);
        #pragma unroll
        for (int c2 = 0; c2 < 2; ++c2)
            bfr[c2] = *(const f16x8*)(bbase + (size_t)((c0 + c2) * 16 + lr) * 64 + s * 32 + lg4 * 8);
        #pragma unroll
        for (int rt = 0; rt < 4; ++rt)
            #pragma unroll
            for (int c2 = 0; c2 < 2; ++c2)
                acc2[rt][c2] = __builtin_amdgcn_mfma_f32_16x16x32_f16(
                    af[rt], bfr[c2], acc2[rt][c2], 0, 0, 0);
    }
    u16* outp = (mat == 0) ? qt : sb;
    #pragma unroll
    for (int rt = 0; rt < 4; ++rt) {
        #pragma unroll
        for (int r = 0; r < 4; ++r) {
            int node = nb + rt * 16 + lg4 * 4 + r;
            if (node >= N_NODES) continue;
            #pragma unroll
            for (int c2 = 0; c2 < 2; ++c2)
                outp[(size_t)node * 64 + (c0 + c2) * 16 + lr] = h16(acc2[rt][c2][r]);
        }
    }
}

// ---------------- pooling ----------------
__global__ __launch_bounds__(256) void pool_sums(const u16* __restrict__ h,
                                                 const int* __restrict__ batch,
                                                 float* __restrict__ gsums) {
    int b = blockIdx.x, t = threadIdx.x;
    int d = t & 63, sub = t >> 6;
    int lo = b * POOL_CHUNK;
    int hi = lo + POOL_CHUNK;
    if (hi > N_NODES) hi = N_NODES;
    float acc = 0.f;
    int curg = -1;
    for (int n = lo + sub; n < hi; n += 4) {
        int g = batch[n];
        if (g != curg) {
            if (curg >= 0) atomicAdd(&gsums[curg * 64 + d], acc);
            acc = 0.f;
            curg = g;
        }
        acc += __half2float(__ushort_as_half(h[(size_t)n * 64 + d]));
    }
    if (curg >= 0) atomicAdd(&gsums[curg * 64 + d], acc);
}

__device__ __forceinline__ int lbound(const int* a, int n, int key) {
    int lo = 0, hi = n;
    while (lo < hi) {
        int mid = (lo + hi) >> 1;
        if (a[mid] < key) lo = mid + 1; else hi = mid;
    }
    return lo;
}

__global__ __launch_bounds__(256) void finalize(const float* __restrict__ gsums,
                                                const int* __restrict__ batch,
                                                const float* __restrict__ Wf,
                                                const float* __restrict__ bf,
                                                float* __restrict__ out) {
    __shared__ float pl[N_GRAPHS][DIM];
    __shared__ int bnd[N_GRAPHS + 1];
    int t = threadIdx.x;
    if (t <= N_GRAPHS) bnd[t] = (t == N_GRAPHS) ? N_NODES : lbound(batch, N_NODES, t);
    __syncthreads();
    for (int i = t; i < N_GRAPHS * DIM; i += 256) {
        int g = i >> 6;
        int cnt = bnd[g + 1] - bnd[g];
        pl[g][i & 63] = gsums[i] / (float)(cnt > 1 ? cnt : 1);
    }
    __syncthreads();
    for (int i = t; i < N_GRAPHS * OUT_DIM; i += 256) {
        int g = i / OUT_DIM, o = i % OUT_DIM;
        float acc = bf[o];
        #pragma unroll
        for (int d = 0; d < DIM; ++d) acc = fmaf(pl[g][d], Wf[d * OUT_DIM + o], acc);
        out[i] = acc;
    }
}

// ---------------- launch ----------------
extern "C" void kernel_launch(void* const* d_in, const int* in_sizes, int n_in,
                              void* d_out, int out_size, void* d_ws, size_t ws_size,
                              hipStream_t stream) {
    const float* x    = (const float*)d_in[0];
    const int*   ei   = (const int*)d_in[1];
    const int*   batch= (const int*)d_in[2];
    const float* Wq   = (const float*)d_in[3];
    const float* bq   = (const float*)d_in[4];
    const float* Wk   = (const float*)d_in[5];
    const float* Wv   = (const float*)d_in[7];
    const float* bv   = (const float*)d_in[8];
    const float* Ws   = (const float*)d_in[9];
    const float* bs   = (const float*)d_in[10];
    const float* Wf   = (const float*)d_in[11];
    const float* bf   = (const float*)d_in[12];
    float* out = (float*)d_out;

    char* ws = (char*)d_ws;
    u16*   qtb   = (u16*)  (ws + 0);            // 6.4 MB
    u16*   hbA   = (u16*)  (ws + 6400000);      // 6.4 MB
    u16*   hbB   = (u16*)  (ws + 12800000);     // 6.4 MB
    u16*   sbb   = (u16*)  (ws + 19200000);     // 6.4 MB
    u16*   hfin16= (u16*)  (ws + 25600000);     // 6.4 MB
    u16*   Mtb   = (u16*)  (ws + 32000000);     // 32 KB
    u16*   WvTb  = (u16*)  (ws + 32032768);     // 32 KB
    u16*   WsTb  = (u16*)  (ws + 32065536);     // 32 KB
    float* ubuf  = (float*)(ws + 32098304);     // 1 KB
    int*   bcur  = (int*)  (ws + 32099328);     // 1 KB
    int*   csr   = (int*)  (ws + 32100352);     // 3.2 MB
    int*   offs  = (int*)  (ws + 35300352);     // 200 KB
    u32*   bscr  = (u32*)  (ws + 35501056);     // 3.92 MB
    float* gsums = (float*)(ws + 39421056);     // 16 KB

    const int* srcI = ei;
    const int* dstI = ei + N_EDGES;

    prep_mats<<<42, 256, 0, stream>>>(Wq, Wk, Wv, Ws, bq, Mtb, WvTb, WsTb, ubuf, gsums, bcur);
    convert_x<<<(N_NODES * 8 + 255) / 256, 256, 0, stream>>>(x, hbA);

    bucket_scatter<<<NBLK_A, 256, 0, stream>>>(srcI, dstI, bcur, bscr);
    csr_build<<<NBUCK, 256, 0, stream>>>(bscr, bcur, offs, csr);

    const int NB = (N_NODES + 63) / 64;
    gemm_init<<<NB, 256, 0, stream>>>(hbA, Mtb, WsTb, ubuf, bs, qtb, sbb);

    const u16* hin = hbA;
    u16* hout = hbB;
    for (int l = 0; l < 4; ++l) {
        int last = (l == 3);
        int ln = last ? 3 : (l + 1);
        layer_fused<<<NB, 256, 0, stream>>>(
            offs, csr, qtb, sbb, hin, hout,
            WvTb + (size_t)l * 4096, bv + l * 64,
            Mtb + (size_t)ln * 4096, ubuf + ln * 64,
            WsTb + (size_t)ln * 4096, bs + ln * 64,
            hfin16, last);
        const u16* tmp = hout; hout = (u16*)hin; hin = tmp;
    }

    pool_sums<<<POOL_BLOCKS, 256, 0, stream>>>(hfin16, batch, gsums);
    finalize<<<1, 256, 0, stream>>>(gsums, batch, Wf, bf, out);
}

// Round 13
// 204.601 us; speedup vs baseline: 1.7854x; 1.2526x over previous
//
#include <hip/hip_runtime.h>
#include <hip/hip_fp16.h>

typedef unsigned short u16;
typedef unsigned int   u32;
typedef _Float16 f16x8 __attribute__((ext_vector_type(8)));
typedef float    f32x4 __attribute__((ext_vector_type(4)));

#define N_NODES  50000
#define N_EDGES  800000
#define DIM      64
#define N_GRAPHS 64
#define OUT_DIM  10
#define POOL_BLOCKS 256
#define POOL_CHUNK  ((N_NODES + POOL_BLOCKS - 1) / POOL_BLOCKS)   // 196

#define BSHIFT 8
#define NBUCK  196
#define BCAP   5000
#define EPB    2048
#define NBLK_A ((N_EDGES + EPB - 1) / EPB)   // 391

__device__ __forceinline__ u16 h16(float f) {
    return __half_as_ushort(__float2half_rn(f));
}
__device__ __forceinline__ __half2 bch(u32 v) {
    union { u32 u; __half2 h; } x; x.u = v; return x.h;
}
__device__ __forceinline__ u32 pkh(float a, float b) {
    union { u32 u; __half2 h; } x; x.h = __floats2half2_rn(a, b); return x.u;
}

// ---------------- bucketed CSR build ----------------
__global__ __launch_bounds__(256) void bucket_scatter(const int* __restrict__ src,
                                                      const int* __restrict__ dst,
                                                      int* __restrict__ bcur,
                                                      u32* __restrict__ bscratch) {
    __shared__ int hist[NBUCK];
    __shared__ int base[NBUCK];
    int t = threadIdx.x;
    for (int i = t; i < NBUCK; i += 256) hist[i] = 0;
    __syncthreads();
    int e0 = blockIdx.x * EPB;
    u32 packed[8];
    int bb[8];
    #pragma unroll
    for (int i = 0; i < 8; ++i) {
        int e = e0 + i * 256 + t;
        if (e < N_EDGES) {
            int d = dst[e], s = src[e];
            bb[i] = d >> BSHIFT;
            packed[i] = ((u32)s << BSHIFT) | (u32)(d & ((1 << BSHIFT) - 1));
            atomicAdd(&hist[bb[i]], 1);
        } else bb[i] = -1;
    }
    __syncthreads();
    for (int i = t; i < NBUCK; i += 256)
        base[i] = (hist[i] > 0) ? atomicAdd(&bcur[i], hist[i]) : 0;
    __syncthreads();
    #pragma unroll
    for (int i = 0; i < 8; ++i) {
        if (bb[i] >= 0) {
            int pos = atomicAdd(&base[bb[i]], 1);
            bscratch[bb[i] * BCAP + pos] = packed[i];
        }
    }
}

__global__ __launch_bounds__(256) void csr_build(const u32* __restrict__ bscratch,
                                                 const int* __restrict__ bcur,
                                                 int* __restrict__ offs,
                                                 int* __restrict__ csr) {
    __shared__ int cnt[256];
    __shared__ int sc[256];
    __shared__ int cur2[256];
    __shared__ int gb[256];
    int b = blockIdx.x, t = threadIdx.x;
    int vb = (t < b) ? bcur[t] : 0;
    gb[t] = vb;
    cnt[t] = 0;
    __syncthreads();
    for (int d = 1; d < 256; d <<= 1) {
        int tmp = (t >= d) ? gb[t - d] : 0;
        __syncthreads();
        gb[t] += tmp;
        __syncthreads();
    }
    int gbase = gb[255];
    int n_b = bcur[b];
    const u32* bp = bscratch + (size_t)b * BCAP;
    for (int i = t; i < n_b; i += 256) atomicAdd(&cnt[bp[i] & 255], 1);
    __syncthreads();
    int v = cnt[t];
    sc[t] = v;
    __syncthreads();
    for (int d = 1; d < 256; d <<= 1) {
        int tmp = (t >= d) ? sc[t - d] : 0;
        __syncthreads();
        sc[t] += tmp;
        __syncthreads();
    }
    int excl = sc[t] - v;
    int node = (b << BSHIFT) + t;
    if (node < N_NODES) offs[node] = gbase + excl;
    if (b == NBUCK - 1 && t == 0) offs[N_NODES] = N_EDGES;
    cur2[t] = gbase + excl;
    __syncthreads();
    for (int i = t; i < n_b; i += 256) {
        u32 p = bp[i];
        int pos = atomicAdd(&cur2[p & 255], 1);
        csr[pos] = (int)(p >> BSHIFT);
    }
}

// ---------------- precompute ----------------

__global__ __launch_bounds__(256) void convert_x(const float* __restrict__ x,
                                                 u16* __restrict__ hb) {
    int c = blockIdx.x * 256 + threadIdx.x;
    if (c >= N_NODES * 8) return;
    const float* src = x + (size_t)c * 8;
    float4 f0 = *(const float4*)src;
    float4 f1 = *(const float4*)(src + 4);
    uint4 pk;
    pk.x = pkh(f0.x, f0.y);
    pk.y = pkh(f0.z, f0.w);
    pk.z = pkh(f1.x, f1.y);
    pk.w = pkh(f1.z, f1.w);
    *(uint4*)(hb + (size_t)c * 8) = pk;
}

// Mt[l][col][k]=sum_c Wq[l][k][c]*Wk[l][col][c]; WvT/WsT transposes; u; zero gsums/bcur
__global__ __launch_bounds__(256) void prep_mats(
    const float* __restrict__ Wq, const float* __restrict__ Wk,
    const float* __restrict__ Wv, const float* __restrict__ Ws,
    const float* __restrict__ bq,
    u16* __restrict__ Mtb, u16* __restrict__ WvTb, u16* __restrict__ WsTb,
    float* __restrict__ ubuf, float* __restrict__ gsums, int* __restrict__ bcur) {
    int id = blockIdx.x * 256 + threadIdx.x;
    if (id < 2048) {
        int kc = id & 7, col = (id >> 3) & 63, l = id >> 9;
        const float* wq = Wq + l * 4096;
        const float* wk = Wk + l * 4096 + col * 64;
        u16 b[8];
        #pragma unroll
        for (int j = 0; j < 8; ++j) {
            float acc = 0.f;
            const float* wqr = wq + (kc * 8 + j) * 64;
            for (int c = 0; c < 64; ++c) acc = fmaf(wqr[c], wk[c], acc);
            b[j] = h16(acc);
        }
        uint4 pk;
        pk.x = (u32)b[0] | ((u32)b[1] << 16);
        pk.y = (u32)b[2] | ((u32)b[3] << 16);
        pk.z = (u32)b[4] | ((u32)b[5] << 16);
        pk.w = (u32)b[6] | ((u32)b[7] << 16);
        *(uint4*)(Mtb + ((size_t)(l * 64 + col)) * 64 + kc * 8) = pk;
    } else if (id < 6144) {
        int i2 = id & 2047;
        int kc = i2 & 7, col = (i2 >> 3) & 63, l = i2 >> 9;
        const float* W = ((id < 4096) ? Wv : Ws) + l * 4096;
        u16* out = (id < 4096) ? WvTb : WsTb;
        u16 b[8];
        #pragma unroll
        for (int j = 0; j < 8; ++j) b[j] = h16(W[(kc * 8 + j) * 64 + col]);
        uint4 pk;
        pk.x = (u32)b[0] | ((u32)b[1] << 16);
        pk.y = (u32)b[2] | ((u32)b[3] << 16);
        pk.z = (u32)b[4] | ((u32)b[5] << 16);
        pk.w = (u32)b[6] | ((u32)b[7] << 16);
        *(uint4*)(out + ((size_t)(l * 64 + col)) * 64 + kc * 8) = pk;
    } else if (id < 6400) {
        int i2 = id - 6144;
        int k = i2 & 63, l = i2 >> 6;
        const float* bqr = bq + l * 64;
        const float* wkr = Wk + l * 4096 + k * 64;
        float acc = 0.f;
        for (int c = 0; c < 64; ++c) acc = fmaf(bqr[c], wkr[c], acc);
        ubuf[l * 64 + k] = acc;
    } else if (id < 6400 + N_GRAPHS * DIM) {
        gsums[id - 6400] = 0.f;
    } else if (id < 6400 + N_GRAPHS * DIM + NBUCK) {
        bcur[id - 6400 - N_GRAPHS * DIM] = 0;
    }
}

// ---------------- gemm_init: qt0 = x@M0 + u0, sb0 = x@Ws0 + bs0 (f16) ----------------
__global__ __launch_bounds__(256) void gemm_init(
    const u16* __restrict__ hb, const u16* __restrict__ Mtb, const u16* __restrict__ WsTb,
    const float* __restrict__ ubuf, const float* __restrict__ bs,
    u16* __restrict__ qt, u16* __restrict__ sb) {
    int t = threadIdx.x;
    int wave = t >> 6, lane = t & 63;
    int nb = blockIdx.x * 64;
    int lr = lane & 15, lg4 = lane >> 4;
    int mat = wave >> 1, c0 = (wave & 1) * 2;

    const u16* bbase = (mat == 0) ? Mtb : WsTb;
    const float* bias = (mat == 0) ? ubuf : bs;

    f32x4 acc[4][2];
    #pragma unroll
    for (int c2 = 0; c2 < 2; ++c2) {
        float bval = bias[(c0 + c2) * 16 + lr];
        #pragma unroll
        for (int rt = 0; rt < 4; ++rt) acc[rt][c2] = (f32x4){bval, bval, bval, bval};
    }
    #pragma unroll
    for (int s = 0; s < 2; ++s) {
        f16x8 af[4], bfr[2];
        #pragma unroll
        for (int rt = 0; rt < 4; ++rt) {
            int node = nb + rt * 16 + lr;
            if (node >= N_NODES) node = 0;
            af[rt] = *(const f16x8*)(hb + (size_t)node * 64 + s * 32 + lg4 * 8);
        }
        #pragma unroll
        for (int c2 = 0; c2 < 2; ++c2)
            bfr[c2] = *(const f16x8*)(bbase + (size_t)((c0 + c2) * 16 + lr) * 64 + s * 32 + lg4 * 8);
        #pragma unroll
        for (int rt = 0; rt < 4; ++rt)
            #pragma unroll
            for (int c2 = 0; c2 < 2; ++c2)
                acc[rt][c2] = __builtin_amdgcn_mfma_f32_16x16x32_f16(
                    af[rt], bfr[c2], acc[rt][c2], 0, 0, 0);
    }
    u16* out = (mat == 0) ? qt : sb;
    #pragma unroll
    for (int rt = 0; rt < 4; ++rt) {
        #pragma unroll
        for (int r = 0; r < 4; ++r) {
            int node = nb + rt * 16 + lg4 * 4 + r;
            if (node >= N_NODES) continue;
            #pragma unroll
            for (int c2 = 0; c2 < 2; ++c2)
                out[(size_t)node * 64 + (c0 + c2) * 16 + lr] = h16(acc[rt][c2][r]);
        }
    }
}

// ---------------- fused layer, 32 nodes/block (2x grid -> 2x occupancy) ----------------
// Phase E: 32 groups x 1 node (static), prefetch depth 2.
// Phase 1: t(32x64)@WvT -> acc1[2]; Phase 2: ldsF; Phase 3: +tz*bv+sb -> out+ldsT;
// Phase 4: waves 0-1 -> qt (cols 0-31 / 32-63), waves 2-3 -> sb.
__global__ __launch_bounds__(256) void layer_fused(
    const int* __restrict__ offs, const int* __restrict__ csr,
    u16* __restrict__ qt, u16* __restrict__ sb,
    const u16* __restrict__ hbin, u16* __restrict__ hbout,
    const u16* __restrict__ WvT, const float* __restrict__ bv,
    const u16* __restrict__ Mtn, const float* __restrict__ un,
    const u16* __restrict__ WsTn, const float* __restrict__ bsn,
    u16* __restrict__ hfin16, int last) {
    __shared__ u16  ldsT[32 * 72];    // 4608 B : t (E->1), then h_next (3->4)
    __shared__ float ldsF[32 * 67];   // 8576 B
    __shared__ float ldsZ[32];
    int t = threadIdx.x;
    int wave = t >> 6, lane = t & 63;
    int nb = blockIdx.x * 32;
    int lr = lane & 15, lg4 = lane >> 4;
    int lg = lane & 7;
    int grp = wave * 8 + (lane >> 3);   // 0..31

    // ---- Phase E: one node per group, prefetch depth 2 ----
    {
        int myn = grp;
        int node = nb + myn;
        bool valid = node < N_NODES;
        int rn = valid ? node : 0;
        uint4 qraw = *(const uint4*)(qt + (size_t)rn * 64 + lg * 8);
        __half2 q01 = bch(qraw.x), q23 = bch(qraw.y), q45 = bch(qraw.z), q67 = bch(qraw.w);
        int e0 = valid ? offs[node] : 0;
        int e1 = valid ? offs[node + 1] : 0;
        float m = -3.0e38f, z = 0.f;
        __half2 zero2 = __float2half2_rn(0.f);
        __half2 a01 = zero2, a23 = zero2, a45 = zero2, a67 = zero2;
        int e = e0;
        int s0i = (e < e1) ? csr[e] : 0;
        uint4 hu0 = *(const uint4*)(hbin + (size_t)s0i * 64 + lg * 8);
        int s1i = (e + 1 < e1) ? csr[e + 1] : 0;
        uint4 hu1 = *(const uint4*)(hbin + (size_t)s1i * 64 + lg * 8);
        while (e < e1) {
            int s2i = (e + 2 < e1) ? csr[e + 2] : 0;
            uint4 hu2 = *(const uint4*)(hbin + (size_t)s2i * 64 + lg * 8);  // 2 ahead
            __half2 h01 = bch(hu0.x), h23 = bch(hu0.y), h45 = bch(hu0.z), h67 = bch(hu0.w);
            __half2 d2 = __hmul2(h01, q01);
            d2 = __hfma2(h23, q23, d2);
            d2 = __hfma2(h45, q45, d2);
            d2 = __hfma2(h67, q67, d2);
            float d = __low2float(d2) + __high2float(d2);
            d += __shfl_xor(d, 1);
            d += __shfl_xor(d, 2);
            d += __shfl_xor(d, 4);
            float alpha = d * 0.125f;               // 1/sqrt(64)
            float diff = alpha - m;
            if (__builtin_expect(diff > 4.f, 0)) {  // keep p <= e^4 for f16 accum
                float c = __expf(-diff);
                z *= c;
                __half2 ch = __float2half2_rn(c);
                a01 = __hmul2(a01, ch); a23 = __hmul2(a23, ch);
                a45 = __hmul2(a45, ch); a67 = __hmul2(a67, ch);
                m = alpha; diff = 0.f;
            }
            float p = __expf(diff);
            z += p;
            __half2 ph = __float2half2_rn(p);
            a01 = __hfma2(ph, h01, a01);
            a23 = __hfma2(ph, h23, a23);
            a45 = __hfma2(ph, h45, a45);
            a67 = __hfma2(ph, h67, a67);
            hu0 = hu1; hu1 = hu2; ++e;
        }
        // always store (invalid rows produce zeros) so ldsT/ldsZ fully init'd
        float invz = 1.f / (z + 1e-16f);
        uint4 pk;
        pk.x = pkh(__low2float(a01) * invz, __high2float(a01) * invz);
        pk.y = pkh(__low2float(a23) * invz, __high2float(a23) * invz);
        pk.z = pkh(__low2float(a45) * invz, __high2float(a45) * invz);
        pk.w = pkh(__low2float(a67) * invz, __high2float(a67) * invz);
        *(uint4*)(ldsT + myn * 72 + lg * 8) = pk;
        if (lg == 0) ldsZ[myn] = (e1 > e0) ? 1.f : 0.f;
    }
    __syncthreads();

    // ---- Phase 1: t(32x64) @ WvT, wave w -> cols w*16..w*16+15 ----
    f32x4 acc1[2];
    #pragma unroll
    for (int rt = 0; rt < 2; ++rt) acc1[rt] = (f32x4){0.f, 0.f, 0.f, 0.f};
    #pragma unroll
    for (int s = 0; s < 2; ++s) {
        f16x8 af[2], bfr;
        #pragma unroll
        for (int rt = 0; rt < 2; ++rt)
            af[rt] = *(const f16x8*)(ldsT + (rt * 16 + lr) * 72 + s * 32 + lg4 * 8);
        bfr = *(const f16x8*)(WvT + (size_t)(wave * 16 + lr) * 64 + s * 32 + lg4 * 8);
        #pragma unroll
        for (int rt = 0; rt < 2; ++rt)
            acc1[rt] = __builtin_amdgcn_mfma_f32_16x16x32_f16(af[rt], bfr, acc1[rt], 0, 0, 0);
    }
    // ---- Phase 2: stash f32 to ldsF ----
    #pragma unroll
    for (int rt = 0; rt < 2; ++rt)
        #pragma unroll
        for (int r = 0; r < 4; ++r)
            ldsF[(rt * 16 + lg4 * 4 + r) * 67 + wave * 16 + lr] = acc1[rt][r];
    __syncthreads();
    // ---- Phase 3: h_next = ldsF + tz*bv + sb -> (hbout|hfin16) + ldsT ----
    {
        int row = t >> 3, cg = (t & 7) * 8;    // 32 rows x 8 cols/thread
        int node = nb + row;
        int rnode = (node < N_NODES) ? node : 0;
        uint4 s0 = *(const uint4*)(sb + (size_t)rnode * 64 + cg);
        float sv[8];
        {
            __half2 x0 = bch(s0.x), x1 = bch(s0.y), x2 = bch(s0.z), x3 = bch(s0.w);
            sv[0] = __low2float(x0); sv[1] = __high2float(x0);
            sv[2] = __low2float(x1); sv[3] = __high2float(x1);
            sv[4] = __low2float(x2); sv[5] = __high2float(x2);
            sv[6] = __low2float(x3); sv[7] = __high2float(x3);
        }
        float tzv = ldsZ[row];
        float vals[8];
        #pragma unroll
        for (int j = 0; j < 8; ++j)
            vals[j] = ldsF[row * 67 + cg + j] + tzv * bv[cg + j] + sv[j];
        uint4 pk;
        pk.x = pkh(vals[0], vals[1]);
        pk.y = pkh(vals[2], vals[3]);
        pk.z = pkh(vals[4], vals[5]);
        pk.w = pkh(vals[6], vals[7]);
        if (node < N_NODES) {
            u16* dst = last ? hfin16 : hbout;
            *(uint4*)(dst + (size_t)node * 64 + cg) = pk;
        }
        *(uint4*)(ldsT + row * 72 + cg) = pk;
    }
    if (last) return;
    __syncthreads();
    // ---- Phase 4: qt_next (waves 0,1) / sb_next (waves 2,3) from ldsT ----
    int mat = wave >> 1, c0 = (wave & 1) * 2;
    const u16* bbase = (mat == 0) ? Mtn : WsTn;
    const float* bias = (mat == 0) ? un : bsn;
    f32x4 acc2[2][2];
    #pragma unroll
    for (int c2 = 0; c2 < 2; ++c2) {
        float bval = bias[(c0 + c2) * 16 + lr];
        #pragma unroll
        for (int rt = 0; rt < 2; ++rt) acc2[rt][c2] = (f32x4){bval, bval, bval, bval};
    }
    #pragma unroll
    for (int s = 0; s < 2; ++s) {
        f16x8 af[2], bfr[2];
        #pragma unroll
        for (int rt = 0; rt < 2; ++rt)
            af[rt] = *(const f16x8*)(ldsT + (rt * 16 + lr) * 72 + s * 32 + lg4 * 8);
        #pragma unroll
        for (int c2 = 0; c2 < 2; ++c2)
            bfr[c2] = *(const f16x8*)(bbase + (size_t)((c0 + c2) * 16 + lr) * 64 + s * 32 + lg4 * 8);
        #pragma unroll
        for (int rt = 0; rt < 2; ++rt)
            #pragma unroll
            for (int c2 = 0; c2 < 2; ++c2)
                acc2[rt][c2] = __builtin_amdgcn_mfma_f32_16x16x32_f16(
                    af[rt], bfr[c2], acc2[rt][c2], 0, 0, 0);
    }
    u16* outp = (mat == 0) ? qt : sb;
    #pragma unroll
    for (int rt = 0; rt < 2; ++rt) {
        #pragma unroll
        for (int r = 0; r < 4; ++r) {
            int node = nb + rt * 16 + lg4 * 4 + r;
            if (node >= N_NODES) continue;
            #pragma unroll
            for (int c2 = 0; c2 < 2; ++c2)
                outp[(size_t)node * 64 + (c0 + c2) * 16 + lr] = h16(acc2[rt][c2][r]);
        }
    }
}

// ---------------- pooling ----------------
__global__ __launch_bounds__(256) void pool_sums(const u16* __restrict__ h,
                                                 const int* __restrict__ batch,
                                                 float* __restrict__ gsums) {
    int b = blockIdx.x, t = threadIdx.x;
    int d = t & 63, sub = t >> 6;
    int lo = b * POOL_CHUNK;
    int hi = lo + POOL_CHUNK;
    if (hi > N_NODES) hi = N_NODES;
    float acc = 0.f;
    int curg = -1;
    for (int n = lo + sub; n < hi; n += 4) {
        int g = batch[n];
        if (g != curg) {
            if (curg >= 0) atomicAdd(&gsums[curg * 64 + d], acc);
            acc = 0.f;
            curg = g;
        }
        acc += __half2float(__ushort_as_half(h[(size_t)n * 64 + d]));
    }
    if (curg >= 0) atomicAdd(&gsums[curg * 64 + d], acc);
}

__device__ __forceinline__ int lbound(const int* a, int n, int key) {
    int lo = 0, hi = n;
    while (lo < hi) {
        int mid = (lo + hi) >> 1;
        if (a[mid] < key) lo = mid + 1; else hi = mid;
    }
    return lo;
}

__global__ __launch_bounds__(256) void finalize(const float* __restrict__ gsums,
                                                const int* __restrict__ batch,
                                                const float* __restrict__ Wf,
                                                const float* __restrict__ bf,
                                                float* __restrict__ out) {
    __shared__ float pl[N_GRAPHS][DIM];
    __shared__ int bnd[N_GRAPHS + 1];
    int t = threadIdx.x;
    if (t <= N_GRAPHS) bnd[t] = (t == N_GRAPHS) ? N_NODES : lbound(batch, N_NODES, t);
    __syncthreads();
    for (int i = t; i < N_GRAPHS * DIM; i += 256) {
        int g = i >> 6;
        int cnt = bnd[g + 1] - bnd[g];
        pl[g][i & 63] = gsums[i] / (float)(cnt > 1 ? cnt : 1);
    }
    __syncthreads();
    for (int i = t; i < N_GRAPHS * OUT_DIM; i += 256) {
        int g = i / OUT_DIM, o = i % OUT_DIM;
        float acc = bf[o];
        #pragma unroll
        for (int d = 0; d < DIM; ++d) acc = fmaf(pl[g][d], Wf[d * OUT_DIM + o], acc);
        out[i] = acc;
    }
}

// ---------------- launch ----------------
extern "C" void kernel_launch(void* const* d_in, const int* in_sizes, int n_in,
                              void* d_out, int out_size, void* d_ws, size_t ws_size,
                              hipStream_t stream) {
    const float* x    = (const float*)d_in[0];
    const int*   ei   = (const int*)d_in[1];
    const int*   batch= (const int*)d_in[2];
    const float* Wq   = (const float*)d_in[3];
    const float* bq   = (const float*)d_in[4];
    const float* Wk   = (const float*)d_in[5];
    const float* Wv   = (const float*)d_in[7];
    const float* bv   = (const float*)d_in[8];
    const float* Ws   = (const float*)d_in[9];
    const float* bs   = (const float*)d_in[10];
    const float* Wf   = (const float*)d_in[11];
    const float* bf   = (const float*)d_in[12];
    float* out = (float*)d_out;

    char* ws = (char*)d_ws;
    u16*   qtb   = (u16*)  (ws + 0);            // 6.4 MB
    u16*   hbA   = (u16*)  (ws + 6400000);      // 6.4 MB
    u16*   hbB   = (u16*)  (ws + 12800000);     // 6.4 MB
    u16*   sbb   = (u16*)  (ws + 19200000);     // 6.4 MB
    u16*   hfin16= (u16*)  (ws + 25600000);     // 6.4 MB
    u16*   Mtb   = (u16*)  (ws + 32000000);     // 32 KB
    u16*   WvTb  = (u16*)  (ws + 32032768);     // 32 KB
    u16*   WsTb  = (u16*)  (ws + 32065536);     // 32 KB
    float* ubuf  = (float*)(ws + 32098304);     // 1 KB
    int*   bcur  = (int*)  (ws + 32099328);     // 1 KB
    int*   csr   = (int*)  (ws + 32100352);     // 3.2 MB
    int*   offs  = (int*)  (ws + 35300352);     // 200 KB
    u32*   bscr  = (u32*)  (ws + 35501056);     // 3.92 MB
    float* gsums = (float*)(ws + 39421056);     // 16 KB

    const int* srcI = ei;
    const int* dstI = ei + N_EDGES;

    prep_mats<<<42, 256, 0, stream>>>(Wq, Wk, Wv, Ws, bq, Mtb, WvTb, WsTb, ubuf, gsums, bcur);
    convert_x<<<(N_NODES * 8 + 255) / 256, 256, 0, stream>>>(x, hbA);

    bucket_scatter<<<NBLK_A, 256, 0, stream>>>(srcI, dstI, bcur, bscr);
    csr_build<<<NBUCK, 256, 0, stream>>>(bscr, bcur, offs, csr);

    const int NB64 = (N_NODES + 63) / 64;
    const int NB32 = (N_NODES + 31) / 32;
    gemm_init<<<NB64, 256, 0, stream>>>(hbA, Mtb, WsTb, ubuf, bs, qtb, sbb);

    const u16* hin = hbA;
    u16* hout = hbB;
    for (int l = 0; l < 4; ++l) {
        int last = (l == 3);
        int ln = last ? 3 : (l + 1);
        layer_fused<<<NB32, 256, 0, stream>>>(
            offs, csr, qtb, sbb, hin, hout,
            WvTb + (size_t)l * 4096, bv + l * 64,
            Mtb + (size_t)ln * 4096, ubuf + ln * 64,
            WsTb + (size_t)ln * 4096, bs + ln * 64,
            hfin16, last);
        const u16* tmp = hout; hout = (u16*)hin; hin = tmp;
    }

    pool_sums<<<POOL_BLOCKS, 256, 0, stream>>>(hfin16, batch, gsums);
    finalize<<<1, 256, 0, stream>>>(gsums, batch, Wf, bf, out);
}